// Round 6
// baseline (1007.955 us; speedup 1.0000x reference)
//
#include <hip/hip_runtime.h>
#include <hip/hip_bf16.h>
#include <math.h>

typedef _Float16 f16;
typedef _Float16 f16x8 __attribute__((ext_vector_type(8)));
typedef float f32x4 __attribute__((ext_vector_type(4)));

constexpr int CH = 8;      // channels
constexpr int TT = 2048;   // time frames
constexpr int FB = 257;    // freq bins
constexpr int HD = 256;    // hidden
constexpr int DHD = 64;    // head dim
constexpr int WN = 512;    // ffn dim
constexpr int HF = 128;    // H/2
constexpr int RR = 8 * TT; // 16384 rows
constexpr int KXP = 288;   // padded K for x / W_in (257 -> 288 = 9*32)

// ---------------------------------------------------------------------------
// Split-f16 MFMA GEMM v3: C = act(A @ W + bias).
// MFMA 16x16x32_f16 (K=32/frag: 1.25x more MFMA-cy per staged byte than
// 32x32x16). Block 128x128, 4 waves (2x2), wave tile 64x64 = 4x4 frags.
// A (hi/lo) staged in LDS (double-buffered, ONE barrier/k-step).
// B read from L2 in packed frag layout [N/16][K/32][hl][64][8] (1KB/wave
// coalesced) -> A-traffic on LDS pipe, B-traffic on L2 pipe, in parallel.
// 3 MFMAs per frag pair: Al*Bh + Ah*Bl + Ah*Bh (error ~2^-22 rel).
// ---------------------------------------------------------------------------
template<int ACT, int WF32, int WF16, int QKV, int XSRC>
__global__ __launch_bounds__(256) void gemm4(
    const f16* __restrict__ Ahi, const f16* __restrict__ Alo, int K,
    const float* __restrict__ Axf, long agrp,
    const f16* __restrict__ Bp,
    const float* __restrict__ bias, const float* __restrict__ bias1,
    const float* __restrict__ bias2,
    float* __restrict__ C0, float* __restrict__ C1, float* __restrict__ C2,
    int ldc, f16* __restrict__ Chi, f16* __restrict__ Clo, int ldf,
    int Nreal, const int* __restrict__ alive)
{
  if (alive && *alive == 0) return;
  __shared__ f16 As[2][2][128][40];   // [dbuf][hi/lo][row][k] (+8 pad)
  const int tid = threadIdx.x;
  const int m0 = blockIdx.x * 128;
  const int n0 = blockIdx.y * 128;
  const int lane = tid & 63, wave = tid >> 6;
  const int wm = wave & 1, wn = wave >> 1;      // 2x2 wave grid
  const int lr = lane & 15, lk = (lane >> 4) * 8;  // frag row / k-offset
  const int srow = tid >> 1, skh = (tid & 1) * 16; // A staging: row, k-half
  const int kb32 = K >> 5;

  f32x4 acc[4][4];
  #pragma unroll
  for (int mf = 0; mf < 4; mf++)
    #pragma unroll
    for (int nf = 0; nf < 4; nf++)
      #pragma unroll
      for (int g = 0; g < 4; g++) acc[mf][nf][g] = 0.f;

  f16x8 sA[4];   // [hi k0..7, hi k8..15, lo k0..7, lo k8..15] for row srow
  const float* xrow = nullptr;
  const f16 *arh = nullptr, *arl = nullptr;
  if constexpr (XSRC) {
    xrow = Axf + (long)((m0 + srow) >> 11) * agrp + (long)((m0 + srow) & 2047) * FB;
  } else {
    arh = Ahi + (long)(m0 + srow) * K + skh;
    arl = Alo + (long)(m0 + srow) * K + skh;
  }

  auto stageA = [&](int k0) {
    if constexpr (XSRC) {
      float v[16];
      #pragma unroll
      for (int j = 0; j < 16; j++) {
        const int k = k0 + skh + j;
        v[j] = (k < FB) ? xrow[k] : 0.f;
      }
      #pragma unroll
      for (int j = 0; j < 8; j++) {
        const f16 h0 = (f16)v[j];     sA[0][j] = h0; sA[2][j] = (f16)(v[j] - (float)h0);
        const f16 h1 = (f16)v[j + 8]; sA[1][j] = h1; sA[3][j] = (f16)(v[j + 8] - (float)h1);
      }
    } else {
      sA[0] = *(const f16x8*)(arh + k0);  sA[1] = *(const f16x8*)(arh + k0 + 8);
      sA[2] = *(const f16x8*)(arl + k0);  sA[3] = *(const f16x8*)(arl + k0 + 8);
    }
  };
  auto writeA = [&](int d) {
    *(f16x8*)&As[d][0][srow][skh]     = sA[0];
    *(f16x8*)&As[d][0][srow][skh + 8] = sA[1];
    *(f16x8*)&As[d][1][srow][skh]     = sA[2];
    *(f16x8*)&As[d][1][srow][skh + 8] = sA[3];
  };
  auto loadB = [&](f16x8 B[4][2], int k0) {
    const int kb = k0 >> 5;
    #pragma unroll
    for (int nf = 0; nf < 4; nf++)
      #pragma unroll
      for (int hl = 0; hl < 2; hl++)
        B[nf][hl] = *(const f16x8*)(Bp +
            ((long)((n0 >> 4) + wn * 4 + nf) * kb32 + kb) * 1024 + hl * 512 + lane * 8);
  };
  auto kstep = [&](f16x8 SB[4][2], f16x8 TB[4][2], int k0, int d) {
    writeA(d);
    __syncthreads();
    if (k0 + 32 < K) { stageA(k0 + 32); loadB(TB, k0 + 32); }
    f16x8 fa[4][2];
    #pragma unroll
    for (int mf = 0; mf < 4; mf++)
      #pragma unroll
      for (int hl = 0; hl < 2; hl++)
        fa[mf][hl] = *(const f16x8*)&As[d][hl][wm * 64 + mf * 16 + lr][lk];
    #pragma unroll
    for (int mf = 0; mf < 4; mf++)
      #pragma unroll
      for (int nf = 0; nf < 4; nf++) {
        acc[mf][nf] = __builtin_amdgcn_mfma_f32_16x16x32_f16(fa[mf][1], SB[nf][0], acc[mf][nf], 0, 0, 0);
        acc[mf][nf] = __builtin_amdgcn_mfma_f32_16x16x32_f16(fa[mf][0], SB[nf][1], acc[mf][nf], 0, 0, 0);
        acc[mf][nf] = __builtin_amdgcn_mfma_f32_16x16x32_f16(fa[mf][0], SB[nf][0], acc[mf][nf], 0, 0, 0);
      }
  };

  f16x8 B0[4][2], B1[4][2];
  stageA(0);
  loadB(B0, 0);
  int d = 0;
  for (int k0 = 0; k0 < K; k0 += 64) {
    kstep(B0, B1, k0, d); d ^= 1;
    if (k0 + 32 < K) { kstep(B1, B0, k0 + 32, d); d ^= 1; }
  }

  // epilogue: C/D layout col=lane&15, row=(lane>>4)*4+g  [m89/m91-verified]
  #pragma unroll
  for (int nf = 0; nf < 4; nf++) {
    const int col = n0 + wn * 64 + nf * 16 + lr;
    const float* bp = bias;
    float* Cp = C0;
    int cc = col;
    if (QKV) {
      const int sel = col >> 8;
      cc = col & 255;
      Cp = sel == 0 ? C0 : (sel == 1 ? C1 : C2);
      bp = sel == 0 ? bias : (sel == 1 ? bias1 : bias2);
    }
    const float bb = (col < Nreal) ? bp[cc] : 0.f;
    #pragma unroll
    for (int mf = 0; mf < 4; mf++)
      #pragma unroll
      for (int g = 0; g < 4; g++) {
        const long row = m0 + wm * 64 + mf * 16 + (lane >> 4) * 4 + g;
        float v = acc[mf][nf][g] + bb;
        if (ACT) v = fmaxf(v, 0.f);
        if (col < Nreal) {
          if (WF32) Cp[row * (long)ldc + cc] = v;
          if (WF16) {
            const f16 hi = (f16)v;
            Chi[row * (long)ldf + col] = hi;
            Clo[row * (long)ldf + col] = (f16)(v - (float)hi);
          }
        }
      }
  }
}

// ---------------------------------------------------------------------------
// Weight transpose + f16 hi/lo split into packed frag layout:
// idx = ((n>>4)*(Kpad>>5) + (k>>5))*1024 + hl*512 + ((n&15)+(((k>>3)&3)<<4))*8 + (k&7)
// ---------------------------------------------------------------------------
__global__ __launch_bounds__(256) void wsplit_k(
    const float* __restrict__ W_in, const float* __restrict__ Wq,
    const float* __restrict__ Wk, const float* __restrict__ Wv,
    const float* __restrict__ Wo, const float* __restrict__ Wf1,
    const float* __restrict__ Wf2, const float* __restrict__ Ws1,
    const float* __restrict__ Wout,
    f16* __restrict__ WinP, f16* __restrict__ WqkvP, f16* __restrict__ WoP,
    f16* __restrict__ Wf1P, f16* __restrict__ Wf2P, f16* __restrict__ Ws1P,
    f16* __restrict__ WoutP)
{
  const int y = blockIdx.y;
  const long idx = (long)blockIdx.x * 256 + threadIdx.x;
  int Npad, Kpad, Ksrc;
  f16* dst;
  switch (y) {
    case 0: Npad = 256; Kpad = 288; Ksrc = 257; dst = WinP;  break;
    case 1: Npad = 768; Kpad = 256; Ksrc = 256; dst = WqkvP; break;
    case 2: Npad = 256; Kpad = 256; Ksrc = 256; dst = WoP;   break;
    case 3: Npad = 512; Kpad = 256; Ksrc = 256; dst = Wf1P;  break;
    case 4: Npad = 256; Kpad = 512; Ksrc = 512; dst = Wf2P;  break;
    case 5: Npad = 128; Kpad = 256; Ksrc = 256; dst = Ws1P;  break;
    default: Npad = 384; Kpad = 256; Ksrc = 256; dst = WoutP; break;
  }
  if (idx >= (long)Npad * Kpad) return;
  const int n = (int)(idx / Kpad), k = (int)(idx % Kpad);
  float v = 0.f;
  if (k < Ksrc) {
    switch (y) {
      case 0: v = W_in[(long)k * 256 + n]; break;
      case 1: { const int sel = n >> 8;
                const float* s = sel == 0 ? Wq : (sel == 1 ? Wk : Wv);
                v = s[(long)k * 256 + (n & 255)]; } break;
      case 2: v = Wo[(long)k * 256 + n]; break;
      case 3: v = Wf1[(long)k * 512 + n]; break;
      case 4: v = Wf2[(long)k * 256 + n]; break;
      case 5: v = Ws1[(long)k * 128 + n]; break;
      default: v = (n < 257) ? Wout[(long)k * 257 + n] : 0.f; break;
    }
  }
  const long base = ((long)(n >> 4) * (Kpad >> 5) + (k >> 5)) * 1024 +
                    ((n & 15) + (((k >> 3) & 3) << 4)) * 8 + (k & 7);
  const f16 hi = (f16)v;
  dst[base] = hi;
  dst[base + 512] = (f16)(v - (float)hi);
}

// ---------------------------------------------------------------------------
// Per-time-frame attention over channels; writes ctx as f16 hi/lo.
// ---------------------------------------------------------------------------
template<int NCc>
__global__ __launch_bounds__(256) void attn_k(
    const float* __restrict__ Q, const float* __restrict__ Ksp,
    const float* __restrict__ Vsp, f16* __restrict__ chi,
    f16* __restrict__ clo, const int* __restrict__ alive)
{
  if (alive && *alive == 0) return;
  const int w = threadIdx.x >> 6;   // head
  const int l = threadIdx.x & 63;   // dh lane
  for (int rr = 0; rr < 4; rr++) {
    const long r = (long)blockIdx.x * 4 + rr;
    const float qv = Q[r * HD + w * DHD + l];
    float sc[NCc];
    #pragma unroll
    for (int c = 0; c < NCc; c++) {
      float p = qv * Ksp[((long)c * RR + r) * HD + w * DHD + l];
      #pragma unroll
      for (int s = 32; s > 0; s >>= 1) p += __shfl_xor(p, s, 64);
      sc[c] = p * 0.125f;   // 1/sqrt(64)
    }
    float m = sc[0];
    #pragma unroll
    for (int c = 1; c < NCc; c++) m = fmaxf(m, sc[c]);
    float a[NCc];
    float den = 0.f;
    #pragma unroll
    for (int c = 0; c < NCc; c++) { a[c] = expf(sc[c] - m); den += a[c]; }
    float cv = 0.f;
    #pragma unroll
    for (int c = 0; c < NCc; c++)
      cv = fmaf(a[c] / den, Vsp[((long)c * RR + r) * HD + w * DHD + l], cv);
    const f16 hi = (f16)cv;
    chi[r * HD + w * DHD + l] = hi;
    clo[r * HD + w * DHD + l] = (f16)(cv - (float)hi);
  }
}

// ---------------------------------------------------------------------------
// O = LayerNorm(X + Y) * g + b over H=256. X from fp32 or hi/lo pair.
// ---------------------------------------------------------------------------
template<int XHL>
__global__ __launch_bounds__(256) void ln_res_k(
    const float* __restrict__ Xf, const f16* __restrict__ Xhi,
    const f16* __restrict__ Xlo, const float* __restrict__ Y,
    const float* __restrict__ g, const float* __restrict__ b,
    float* __restrict__ O, f16* __restrict__ Ohi, f16* __restrict__ Olo,
    const int* __restrict__ alive)
{
  if (alive && *alive == 0) return;
  __shared__ float red[2][8];
  const int tid = threadIdx.x;
  const int w = tid >> 6;
  for (int rr = 0; rr < 8; rr++) {
    const int p = rr & 1;
    const long r = (long)blockIdx.x * 8 + rr;
    float xv;
    if (XHL) xv = (float)Xhi[r * HD + tid] + (float)Xlo[r * HD + tid];
    else     xv = Xf[r * HD + tid];
    const float v = xv + Y[r * HD + tid];
    float s = v, sq = v * v;
    #pragma unroll
    for (int i = 32; i > 0; i >>= 1) {
      s += __shfl_xor(s, i, 64);
      sq += __shfl_xor(sq, i, 64);
    }
    if ((tid & 63) == 0) { red[p][w] = s; red[p][4 + w] = sq; }
    __syncthreads();
    const float mean = (red[p][0] + red[p][1] + red[p][2] + red[p][3]) * (1.f / HD);
    const float ex2 = (red[p][4] + red[p][5] + red[p][6] + red[p][7]) * (1.f / HD);
    const float var = ex2 - mean * mean;
    const float inv = 1.f / sqrtf(var + 1e-5f);
    const float o = (v - mean) * inv * g[tid] + b[tid];
    O[r * HD + tid] = o;
    const f16 hi = (f16)o;
    Ohi[r * HD + tid] = hi;
    Olo[r * HD + tid] = (f16)(o - (float)hi);
  }
}

// ---------------------------------------------------------------------------
// ACT ponder update. Also writes pc to its final output slot every live call
// (last live value stands; dead iterations preserve it).
// ---------------------------------------------------------------------------
template<int FIRST>
__global__ __launch_bounds__(256) void act_k(
    const float* __restrict__ s1, const float* __restrict__ Ws2,
    const float* __restrict__ bs2, const float* __restrict__ psa,
    const float* __restrict__ psb, const float* __restrict__ hh,
    float* __restrict__ cum, float* __restrict__ rem,
    float* __restrict__ still, float* __restrict__ pc,
    float* __restrict__ out, f16* __restrict__ outhi, f16* __restrict__ outlo,
    float* __restrict__ pcdst, int lastIter,
    const int* __restrict__ alive, int* __restrict__ myFlag)
{
  if (!FIRST && alive && *alive == 0) return;
  __shared__ float red[2][4];
  const int tid = threadIdx.x;
  const int w = tid >> 6;
  for (int rr = 0; rr < 8; rr++) {
    const int p = rr & 1;
    const long r = (long)blockIdx.x * 8 + rr;
    float curv;
    if (!lastIter) {
      float pv = (tid < HF) ? s1[r * HF + tid] * Ws2[tid] : 0.f;
      #pragma unroll
      for (int i = 32; i > 0; i >>= 1) pv += __shfl_xor(pv, i, 64);
      if ((tid & 63) == 0) red[p][w] = pv;
      __syncthreads();
      const float s = red[p][0] + red[p][1] + red[p][2] + red[p][3] + bs2[0];
      const float z = (s - psa[0]) / (psb[0] + 1e-8f);
      curv = 1.f / (1.f + expf(-z));
    } else {
      curv = 1.f;
    }
    const float cu = FIRST ? 0.f : cum[r];
    const float re = FIRST ? 1.f : rem[r];
    const float st = FIRST ? 1.f : still[r];
    const float pp = FIRST ? 0.f : pc[r];
    const float cum_n = cu + curv * st;
    float pc_n = pp + st;
    const float still_n = (cum_n < 0.9999f) ? 1.f : 0.f;
    const float wgt = curv * still_n + re * (1.f - still_n);
    const float prev = FIRST ? 0.f : out[r * HD + tid];
    const float newv = prev + hh[r * HD + tid] * wgt;
    out[r * HD + tid] = newv;
    const f16 hi = (f16)newv;
    outhi[r * HD + tid] = hi;
    outlo[r * HD + tid] = (f16)(newv - (float)hi);
    const float rem_n = re - curv * still_n;
    pc_n += rem_n * (1.f - still_n);
    if (tid == 0) {
      cum[r] = cum_n; rem[r] = rem_n; still[r] = still_n; pc[r] = pc_n;
      pcdst[r] = pc_n;
      if (still_n > 0.5f) *myFlag = 1;
    }
  }
}

__global__ void init_k(int* flags) {
  if (threadIdx.x < 8) flags[threadIdx.x] = 0;
}

// ---------------------------------------------------------------------------
extern "C" void kernel_launch(void* const* d_in, const int* in_sizes, int n_in,
                              void* d_out, int out_size, void* d_ws, size_t ws_size,
                              hipStream_t stream) {
  const float* x    = (const float*)d_in[0];
  const float* W_in = (const float*)d_in[1];
  const float* b_in = (const float*)d_in[2];
  const float* W_out= (const float*)d_in[3];
  const float* b_out= (const float*)d_in[4];
  const float* Wq   = (const float*)d_in[5];
  const float* bq   = (const float*)d_in[6];
  const float* Wk   = (const float*)d_in[7];
  const float* bk   = (const float*)d_in[8];
  const float* Wv   = (const float*)d_in[9];
  const float* bv   = (const float*)d_in[10];
  const float* Wo   = (const float*)d_in[11];
  const float* bo   = (const float*)d_in[12];
  const float* ln1g = (const float*)d_in[13];
  const float* ln1b = (const float*)d_in[14];
  const float* Wf1  = (const float*)d_in[15];
  const float* bf1  = (const float*)d_in[16];
  const float* Wf2  = (const float*)d_in[17];
  const float* bf2  = (const float*)d_in[18];
  const float* ln2g = (const float*)d_in[19];
  const float* ln2b = (const float*)d_in[20];
  const float* Ws1  = (const float*)d_in[21];
  const float* bs1  = (const float*)d_in[22];
  const float* Ws2  = (const float*)d_in[23];
  const float* bs2  = (const float*)d_in[24];
  const float* psa  = (const float*)d_in[25];
  const float* psb  = (const float*)d_in[26];

  float* ws = (float*)d_ws;
  long off = 0;
  auto alloc = [&](long n) { float* p = ws + off; off += n; return p; };
  float* Ks   = alloc((long)CH * RR * HD);
  float* Vs   = alloc((long)CH * RR * HD);
  float* Qb   = alloc((long)RR * HD);
  float* gb   = alloc((long)RR * HD);
  float* h1   = alloc((long)RR * HD);
  float* hh   = alloc((long)RR * HD);
  float* outb = alloc((long)RR * HD);
  f16* lin1hi = (f16*)alloc((long)RR * HD / 2);
  f16* lin1lo = (f16*)alloc((long)RR * HD / 2);
  f16* ctxhi  = (f16*)alloc((long)RR * HD / 2);
  f16* ctxlo  = (f16*)alloc((long)RR * HD / 2);
  f16* h1hi   = (f16*)alloc((long)RR * HD / 2);
  f16* h1lo   = (f16*)alloc((long)RR * HD / 2);
  f16* hhhi   = (f16*)alloc((long)RR * HD / 2);
  f16* hhlo   = (f16*)alloc((long)RR * HD / 2);
  f16* t1hi   = (f16*)alloc((long)RR * WN / 2);
  f16* t1lo   = (f16*)alloc((long)RR * WN / 2);
  f16* outhi  = (f16*)alloc((long)RR * HD / 2);
  f16* outlo  = (f16*)alloc((long)RR * HD / 2);
  f16* WinP   = (f16*)alloc(2 * 256 * 288 / 2);
  f16* WqkvP  = (f16*)alloc(2 * 768 * 256 / 2);
  f16* WoP    = (f16*)alloc(2 * 256 * 256 / 2);
  f16* Wf1P   = (f16*)alloc(2 * 512 * 256 / 2);
  f16* Wf2P   = (f16*)alloc(2 * 256 * 512 / 2);
  f16* Ws1P   = (f16*)alloc(2 * 128 * 256 / 2);
  f16* WoutP  = (f16*)alloc(2 * 384 * 256 / 2);
  float* cum  = alloc(RR);
  float* rem  = alloc(RR);
  float* still= alloc(RR);
  float* pc   = alloc(RR);
  int* flags  = (int*)alloc(8);
  float* s1   = Qb;   // alias: Qb consumed by attn before s1 written

  init_k<<<1, 256, 0, stream>>>(flags);
  wsplit_k<<<dim3(768, 7), 256, 0, stream>>>(
      W_in, Wq, Wk, Wv, Wo, Wf1, Wf2, Ws1, W_out,
      WinP, WqkvP, WoP, Wf1P, Wf2P, Ws1P, WoutP);

  float* pcdst = (float*)d_out + (long)RR * FB;

  for (int ci = 0; ci < CH; ci++) {
    const int* al = (ci == 0) ? nullptr : (flags + ci - 1);
    // lin1 = relu(x[:,ci] @ W_in + b_in) -> f16 hi/lo
    gemm4<1, 0, 1, 0, 1><<<dim3(128, 2), 256, 0, stream>>>(
        nullptr, nullptr, KXP, x + (long)ci * TT * FB, (long)CH * TT * FB,
        WinP, b_in, b_in, b_in, nullptr, nullptr, nullptr, HD,
        lin1hi, lin1lo, HD, HD, al);
    // fused Q/K/V projections (N=768)
    gemm4<0, 1, 0, 1, 0><<<dim3(128, 6), 256, 0, stream>>>(
        lin1hi, lin1lo, HD, nullptr, 0, WqkvP, bq, bk, bv,
        Qb, Ks + (long)ci * RR * HD, Vs + (long)ci * RR * HD, HD,
        nullptr, nullptr, HD, 768, al);
    // attention over channels 0..ci
    switch (ci) {
      case 0: attn_k<1><<<4096, 256, 0, stream>>>(Qb, Ks, Vs, ctxhi, ctxlo, al); break;
      case 1: attn_k<2><<<4096, 256, 0, stream>>>(Qb, Ks, Vs, ctxhi, ctxlo, al); break;
      case 2: attn_k<3><<<4096, 256, 0, stream>>>(Qb, Ks, Vs, ctxhi, ctxlo, al); break;
      case 3: attn_k<4><<<4096, 256, 0, stream>>>(Qb, Ks, Vs, ctxhi, ctxlo, al); break;
      case 4: attn_k<5><<<4096, 256, 0, stream>>>(Qb, Ks, Vs, ctxhi, ctxlo, al); break;
      case 5: attn_k<6><<<4096, 256, 0, stream>>>(Qb, Ks, Vs, ctxhi, ctxlo, al); break;
      case 6: attn_k<7><<<4096, 256, 0, stream>>>(Qb, Ks, Vs, ctxhi, ctxlo, al); break;
      default: attn_k<8><<<4096, 256, 0, stream>>>(Qb, Ks, Vs, ctxhi, ctxlo, al); break;
    }
    // h1 = LN(lin1 + ctx @ Wo + bo)
    gemm4<0, 1, 0, 0, 0><<<dim3(128, 2), 256, 0, stream>>>(
        ctxhi, ctxlo, HD, nullptr, 0, WoP, bo, bo, bo,
        gb, nullptr, nullptr, HD, nullptr, nullptr, HD, HD, al);
    ln_res_k<1><<<2048, 256, 0, stream>>>(nullptr, lin1hi, lin1lo, gb,
                                          ln1g, ln1b, h1, h1hi, h1lo, al);
    // hh = LN(h1 + relu(h1@Wf1+bf1)@Wf2+bf2)
    gemm4<1, 0, 1, 0, 0><<<dim3(128, 4), 256, 0, stream>>>(
        h1hi, h1lo, HD, nullptr, 0, Wf1P, bf1, bf1, bf1,
        nullptr, nullptr, nullptr, WN, t1hi, t1lo, WN, WN, al);
    gemm4<0, 1, 0, 0, 0><<<dim3(128, 2), 256, 0, stream>>>(
        t1hi, t1lo, WN, nullptr, 0, Wf2P, bf2, bf2, bf2,
        gb, nullptr, nullptr, HD, nullptr, nullptr, HD, HD, al);
    ln_res_k<0><<<2048, 256, 0, stream>>>(h1, nullptr, nullptr, gb,
                                          ln2g, ln2b, hh, hhhi, hhlo, al);
    // ponder head + ACT state update
    if (ci < CH - 1)
      gemm4<1, 1, 0, 0, 0><<<dim3(128, 1), 256, 0, stream>>>(
          hhhi, hhlo, HD, nullptr, 0, Ws1P, bs1, bs1, bs1,
          s1, nullptr, nullptr, HF, nullptr, nullptr, HD, HF, al);
    if (ci == 0)
      act_k<1><<<2048, 256, 0, stream>>>(s1, Ws2, bs2, psa, psb, hh, cum, rem,
                                         still, pc, outb, outhi, outlo, pcdst,
                                         0, nullptr, flags + 0);
    else
      act_k<0><<<2048, 256, 0, stream>>>(s1, Ws2, bs2, psa, psb, hh, cum, rem,
                                         still, pc, outb, outhi, outlo, pcdst,
                                         (ci == CH - 1) ? 1 : 0, al, flags + ci);
  }
  // encoder_out = relu(out @ W_out + b_out)
  gemm4<1, 1, 0, 0, 0><<<dim3(128, 3), 256, 0, stream>>>(
      outhi, outlo, HD, nullptr, 0, WoutP, b_out, b_out, b_out,
      (float*)d_out, nullptr, nullptr, FB, nullptr, nullptr, HD, FB, nullptr);
}

// Round 7
// 853.503 us; speedup vs baseline: 1.1810x; 1.1810x over previous
//
#include <hip/hip_runtime.h>
#include <hip/hip_bf16.h>
#include <math.h>

typedef _Float16 f16;
typedef _Float16 f16x4 __attribute__((ext_vector_type(4)));
typedef _Float16 f16x8 __attribute__((ext_vector_type(8)));
typedef float f32x16 __attribute__((ext_vector_type(16)));

constexpr int CH = 8;      // channels
constexpr int TT = 2048;   // time frames
constexpr int FB = 257;    // freq bins
constexpr int HD = 256;    // hidden
constexpr int DHD = 64;    // head dim
constexpr int WN = 512;    // ffn dim
constexpr int HF = 128;    // H/2
constexpr int RR = 8 * TT; // 16384 rows
constexpr int KXP = 288;   // padded K for x / W_in

// ---------------------------------------------------------------------------
// gemm2 (R5-measured-best): C = act(A @ W + bias). Tile 128x64, 4 waves,
// wave tile 32x64 (2 N-frags of 32x32x16). A staged in LDS (dbuf, ONE
// barrier/k-step); B direct from L2, packed [N/32][K/8][hl][32][8].
// 3 MFMAs per frag pair: Al*Bh + Ah*Bl + Ah*Bh (err ~2^-22 rel).
// ---------------------------------------------------------------------------
template<int ACT, int WF32, int WF16, int QKV, int XSRC>
__global__ __launch_bounds__(256, 2) void gemm2(
    const f16* __restrict__ Ahi, const f16* __restrict__ Alo, int K,
    const float* __restrict__ Axf, long agrp,
    const f16* __restrict__ Bp,
    const float* __restrict__ bias, const float* __restrict__ bias1,
    const float* __restrict__ bias2,
    float* __restrict__ C0, float* __restrict__ C1, float* __restrict__ C2,
    int ldc, f16* __restrict__ Chi, f16* __restrict__ Clo, int ldf,
    int Nreal, const int* __restrict__ alive)
{
  if (alive && *alive == 0) return;
  __shared__ f16 As[2][2][128][40];
  const int tid = threadIdx.x;
  const int m0 = blockIdx.x * 128;
  const int n0 = blockIdx.y * 64;
  const int q = tid & 3, r = tid >> 2;
  const int lane = tid & 63, wm = tid >> 6;
  const int lr = lane & 31, lg = lane >> 5;
  const int nb0 = n0 >> 5, kd8 = K >> 3;

  f32x16 acc[2];
  #pragma unroll
  for (int nf = 0; nf < 2; nf++)
    #pragma unroll
    for (int g = 0; g < 16; g++) acc[nf][g] = 0.f;

  const long aoff = (long)(m0 + r) * K + q * 8;
  const long hstep = (long)64 * K;
  const float* xR0 = nullptr;
  const float* xR1 = nullptr;
  if constexpr (XSRC) {
    const int r0 = m0 + r, r1 = r0 + 64;
    xR0 = Axf + (long)(r0 >> 11) * agrp + (long)(r0 & 2047) * FB;
    xR1 = Axf + (long)(r1 >> 11) * agrp + (long)(r1 & 2047) * FB;
  }

  f16x8 sA[4];
  auto loadA = [&](int k0) {
    if constexpr (XSRC) {
      float a0[8], a1[8];
      #pragma unroll
      for (int j = 0; j < 8; j++) {
        const int k = k0 + q * 8 + j;
        a0[j] = (k < FB) ? xR0[k] : 0.f;
        a1[j] = (k < FB) ? xR1[k] : 0.f;
      }
      #pragma unroll
      for (int j = 0; j < 8; j++) {
        const f16 h0 = (f16)a0[j]; sA[0][j] = h0; sA[2][j] = (f16)(a0[j] - (float)h0);
        const f16 h1 = (f16)a1[j]; sA[1][j] = h1; sA[3][j] = (f16)(a1[j] - (float)h1);
      }
    } else {
      const long a = aoff + k0;
      sA[0] = *(const f16x8*)(Ahi + a);  sA[1] = *(const f16x8*)(Ahi + a + hstep);
      sA[2] = *(const f16x8*)(Alo + a);  sA[3] = *(const f16x8*)(Alo + a + hstep);
    }
  };
  auto loadB = [&](f16x8 B[2][2][2], int k0) {
    const int kb = (k0 >> 3) + lg;
    #pragma unroll
    for (int kh = 0; kh < 2; kh++)
      #pragma unroll
      for (int nf = 0; nf < 2; nf++)
        #pragma unroll
        for (int hl = 0; hl < 2; hl++)
          B[kh][nf][hl] = *(const f16x8*)(Bp +
              ((long)((nb0 + nf) * kd8 + kb + kh * 2) * 512 + hl * 256 + lr * 8));
  };
  auto kstep = [&](f16x8 SB[2][2][2], f16x8 TB[2][2][2], int k0, int d) {
    *(f16x8*)&As[d][0][r][q * 8]      = sA[0];
    *(f16x8*)&As[d][0][r + 64][q * 8] = sA[1];
    *(f16x8*)&As[d][1][r][q * 8]      = sA[2];
    *(f16x8*)&As[d][1][r + 64][q * 8] = sA[3];
    __syncthreads();
    if (k0 + 32 < K) { loadA(k0 + 32); loadB(TB, k0 + 32); }
    f16x8 fa[2][2];
    #pragma unroll
    for (int kh = 0; kh < 2; kh++)
      #pragma unroll
      for (int hl = 0; hl < 2; hl++)
        fa[kh][hl] = *(const f16x8*)&As[d][hl][wm * 32 + lr][kh * 16 + lg * 8];
    #pragma unroll
    for (int kh = 0; kh < 2; kh++)
      #pragma unroll
      for (int nf = 0; nf < 2; nf++) {
        acc[nf] = __builtin_amdgcn_mfma_f32_32x32x16_f16(fa[kh][1], SB[kh][nf][0], acc[nf], 0, 0, 0);
        acc[nf] = __builtin_amdgcn_mfma_f32_32x32x16_f16(fa[kh][0], SB[kh][nf][1], acc[nf], 0, 0, 0);
        acc[nf] = __builtin_amdgcn_mfma_f32_32x32x16_f16(fa[kh][0], SB[kh][nf][0], acc[nf], 0, 0, 0);
      }
  };

  f16x8 B0[2][2][2], B1[2][2][2];
  loadA(0);
  loadB(B0, 0);
  int d = 0;
  for (int k0 = 0; k0 < K; k0 += 64) {
    kstep(B0, B1, k0, d); d ^= 1;
    if (k0 + 32 < K) { kstep(B1, B0, k0 + 32, d); d ^= 1; }
  }

  #pragma unroll
  for (int nf = 0; nf < 2; nf++) {
    const int col = n0 + nf * 32 + lr;
    const float* bp = bias;
    float* Cp = C0;
    int cc = col;
    if (QKV) {
      const int sel = col >> 8;
      cc = col & 255;
      Cp = sel == 0 ? C0 : (sel == 1 ? C1 : C2);
      bp = sel == 0 ? bias : (sel == 1 ? bias1 : bias2);
    }
    const float bb = (col < Nreal) ? bp[cc] : 0.f;
    #pragma unroll
    for (int g = 0; g < 16; g++) {
      const long row = m0 + wm * 32 + (g & 3) + 8 * (g >> 2) + 4 * lg;
      float v = acc[nf][g] + bb;
      if (ACT) v = fmaxf(v, 0.f);
      if (col < Nreal) {
        if (WF32) Cp[row * (long)ldc + cc] = v;
        if (WF16) {
          const f16 hi = (f16)v;
          Chi[row * (long)ldf + col] = hi;
          Clo[row * (long)ldf + col] = (f16)(v - (float)hi);
        }
      }
    }
  }
}

// ---------------------------------------------------------------------------
// FUSED: O(hi/lo) = LN(R + A@W + bias) * g + b.  N = 256 (full row in block).
// Block 64 rows x 256 cols, 512 thr = 8 waves (2 wm x 4 wn), wave 32x64.
// Same A-LDS / packed-B structure as gemm2. Row LN via shfl + LDS reduce.
// ---------------------------------------------------------------------------
__global__ __launch_bounds__(512) void gemm_ln(
    const f16* __restrict__ Ahi, const f16* __restrict__ Alo, int K,
    const f16* __restrict__ Bp, const float* __restrict__ bias,
    const f16* __restrict__ Rhi, const f16* __restrict__ Rlo,
    const float* __restrict__ gg, const float* __restrict__ bb_,
    f16* __restrict__ Ohi, f16* __restrict__ Olo,
    const int* __restrict__ alive)
{
  if (alive && *alive == 0) return;
  __shared__ f16 As[2][2][64][40];
  __shared__ float red[64][4][2];
  const int tid = threadIdx.x;
  const int m0 = blockIdx.x * 64;
  const int lane = tid & 63, wave = tid >> 6;
  const int wm = wave & 1, wn = wave >> 1;
  const int lr = lane & 31, lg = lane >> 5;
  const int srow = tid >> 3, sk = (tid & 7) * 4;
  const int kd8 = K >> 3;

  f32x16 acc[2];
  #pragma unroll
  for (int nf = 0; nf < 2; nf++)
    #pragma unroll
    for (int g = 0; g < 16; g++) acc[nf][g] = 0.f;

  const f16* arh = Ahi + (long)(m0 + srow) * K + sk;
  const f16* arl = Alo + (long)(m0 + srow) * K + sk;
  f16x4 sAh, sAl;
  auto loadA = [&](int k0) {
    sAh = *(const f16x4*)(arh + k0);
    sAl = *(const f16x4*)(arl + k0);
  };
  auto loadB = [&](f16x8 B[2][2][2], int k0) {
    const int kb = (k0 >> 3) + lg;
    #pragma unroll
    for (int kh = 0; kh < 2; kh++)
      #pragma unroll
      for (int nf = 0; nf < 2; nf++)
        #pragma unroll
        for (int hl = 0; hl < 2; hl++)
          B[kh][nf][hl] = *(const f16x8*)(Bp +
              ((long)((wn * 2 + nf) * kd8 + kb + kh * 2) * 512 + hl * 256 + lr * 8));
  };
  auto kstep = [&](f16x8 SB[2][2][2], f16x8 TB[2][2][2], int k0, int d) {
    *(f16x4*)&As[d][0][srow][sk] = sAh;
    *(f16x4*)&As[d][1][srow][sk] = sAl;
    __syncthreads();
    if (k0 + 32 < K) { loadA(k0 + 32); loadB(TB, k0 + 32); }
    f16x8 fa[2][2];
    #pragma unroll
    for (int kh = 0; kh < 2; kh++)
      #pragma unroll
      for (int hl = 0; hl < 2; hl++)
        fa[kh][hl] = *(const f16x8*)&As[d][hl][wm * 32 + lr][kh * 16 + lg * 8];
    #pragma unroll
    for (int kh = 0; kh < 2; kh++)
      #pragma unroll
      for (int nf = 0; nf < 2; nf++) {
        acc[nf] = __builtin_amdgcn_mfma_f32_32x32x16_f16(fa[kh][1], SB[kh][nf][0], acc[nf], 0, 0, 0);
        acc[nf] = __builtin_amdgcn_mfma_f32_32x32x16_f16(fa[kh][0], SB[kh][nf][1], acc[nf], 0, 0, 0);
        acc[nf] = __builtin_amdgcn_mfma_f32_32x32x16_f16(fa[kh][0], SB[kh][nf][0], acc[nf], 0, 0, 0);
      }
  };

  f16x8 B0[2][2][2], B1[2][2][2];
  loadA(0);
  loadB(B0, 0);
  int d = 0;
  for (int k0 = 0; k0 < K; k0 += 64) {
    kstep(B0, B1, k0, d); d ^= 1;
    if (k0 + 32 < K) { kstep(B1, B0, k0 + 32, d); d ^= 1; }
  }

  // epilogue: bias + residual, per-row LN over 256 cols
  float pr[16], qr[16];
  #pragma unroll
  for (int g = 0; g < 16; g++) {
    const int row_l = wm * 32 + (g & 3) + 8 * (g >> 2) + 4 * lg;
    const long rbase = (long)(m0 + row_l) * HD;
    float s = 0.f, sq = 0.f;
    #pragma unroll
    for (int nf = 0; nf < 2; nf++) {
      const int col = wn * 64 + nf * 32 + lr;
      float v = acc[nf][g] + bias[col]
              + (float)Rhi[rbase + col] + (float)Rlo[rbase + col];
      acc[nf][g] = v;
      s += v; sq += v * v;
    }
    pr[g] = s; qr[g] = sq;
  }
  #pragma unroll
  for (int g = 0; g < 16; g++)
    #pragma unroll
    for (int i = 1; i <= 16; i <<= 1) {
      pr[g] += __shfl_xor(pr[g], i, 64);
      qr[g] += __shfl_xor(qr[g], i, 64);
    }
  if (lr == 0) {
    #pragma unroll
    for (int g = 0; g < 16; g++) {
      const int row_l = wm * 32 + (g & 3) + 8 * (g >> 2) + 4 * lg;
      red[row_l][wn][0] = pr[g];
      red[row_l][wn][1] = qr[g];
    }
  }
  __syncthreads();
  #pragma unroll
  for (int g = 0; g < 16; g++) {
    const int row_l = wm * 32 + (g & 3) + 8 * (g >> 2) + 4 * lg;
    const float mean = (red[row_l][0][0] + red[row_l][1][0] +
                        red[row_l][2][0] + red[row_l][3][0]) * (1.f / HD);
    const float ex2 = (red[row_l][0][1] + red[row_l][1][1] +
                       red[row_l][2][1] + red[row_l][3][1]) * (1.f / HD);
    const float inv = 1.f / sqrtf(ex2 - mean * mean + 1e-5f);
    const long rbase = (long)(m0 + row_l) * HD;
    #pragma unroll
    for (int nf = 0; nf < 2; nf++) {
      const int col = wn * 64 + nf * 32 + lr;
      const float o = (acc[nf][g] - mean) * inv * gg[col] + bb_[col];
      const f16 hi = (f16)o;
      Ohi[rbase + col] = hi;
      Olo[rbase + col] = (f16)(o - (float)hi);
    }
  }
}

// ---------------------------------------------------------------------------
// FUSED: s1 = relu(hh@Ws1+bs1); s = s1.Ws2+bs2; cur = sigmoid((s-psa)/psb');
// + full ACT ponder state update + out accumulation. N = 128 (full in block).
// Block 64 rows x 128 cols, 256 thr = 4 waves (2 wm x 2 wn), wave 32x64.
// ---------------------------------------------------------------------------
template<int FIRST>
__global__ __launch_bounds__(256) void s1_act(
    const f16* __restrict__ hhhi, const f16* __restrict__ hhlo,
    const f16* __restrict__ Bp, const float* __restrict__ bs1,
    const float* __restrict__ Ws2, const float* __restrict__ bs2,
    const float* __restrict__ psa, const float* __restrict__ psb,
    float* __restrict__ cum, float* __restrict__ rem,
    float* __restrict__ still, float* __restrict__ pc,
    f16* __restrict__ outhi, f16* __restrict__ outlo,
    float* __restrict__ pcdst,
    const int* __restrict__ alive, int* __restrict__ myFlag)
{
  if (!FIRST && alive && *alive == 0) return;
  __shared__ f16 As[2][2][64][40];
  __shared__ float red[64][2];
  const int tid = threadIdx.x;
  const int m0 = blockIdx.x * 64;
  const int lane = tid & 63, wave = tid >> 6;
  const int wm = wave & 1, wn = wave >> 1;
  const int lr = lane & 31, lg = lane >> 5;
  const int srow = tid >> 2, sk = (tid & 3) * 8;
  const int K = HD, kd8 = K >> 3;

  f32x16 acc[2];
  #pragma unroll
  for (int nf = 0; nf < 2; nf++)
    #pragma unroll
    for (int g = 0; g < 16; g++) acc[nf][g] = 0.f;

  const f16* arh = hhhi + (long)(m0 + srow) * K + sk;
  const f16* arl = hhlo + (long)(m0 + srow) * K + sk;
  f16x8 sAh, sAl;
  auto loadA = [&](int k0) {
    sAh = *(const f16x8*)(arh + k0);
    sAl = *(const f16x8*)(arl + k0);
  };
  auto loadB = [&](f16x8 B[2][2][2], int k0) {
    const int kb = (k0 >> 3) + lg;
    #pragma unroll
    for (int kh = 0; kh < 2; kh++)
      #pragma unroll
      for (int nf = 0; nf < 2; nf++)
        #pragma unroll
        for (int hl = 0; hl < 2; hl++)
          B[kh][nf][hl] = *(const f16x8*)(Bp +
              ((long)((wn * 2 + nf) * kd8 + kb + kh * 2) * 512 + hl * 256 + lr * 8));
  };
  auto kstep = [&](f16x8 SB[2][2][2], f16x8 TB[2][2][2], int k0, int d) {
    *(f16x8*)&As[d][0][srow][sk] = sAh;
    *(f16x8*)&As[d][1][srow][sk] = sAl;
    __syncthreads();
    if (k0 + 32 < K) { loadA(k0 + 32); loadB(TB, k0 + 32); }
    f16x8 fa[2][2];
    #pragma unroll
    for (int kh = 0; kh < 2; kh++)
      #pragma unroll
      for (int hl = 0; hl < 2; hl++)
        fa[kh][hl] = *(const f16x8*)&As[d][hl][wm * 32 + lr][kh * 16 + lg * 8];
    #pragma unroll
    for (int kh = 0; kh < 2; kh++)
      #pragma unroll
      for (int nf = 0; nf < 2; nf++) {
        acc[nf] = __builtin_amdgcn_mfma_f32_32x32x16_f16(fa[kh][1], SB[kh][nf][0], acc[nf], 0, 0, 0);
        acc[nf] = __builtin_amdgcn_mfma_f32_32x32x16_f16(fa[kh][0], SB[kh][nf][1], acc[nf], 0, 0, 0);
        acc[nf] = __builtin_amdgcn_mfma_f32_32x32x16_f16(fa[kh][0], SB[kh][nf][0], acc[nf], 0, 0, 0);
      }
  };

  f16x8 B0[2][2][2], B1[2][2][2];
  loadA(0);
  loadB(B0, 0);
  int d = 0;
  for (int k0 = 0; k0 < K; k0 += 64) {
    kstep(B0, B1, k0, d); d ^= 1;
    if (k0 + 32 < K) { kstep(B1, B0, k0 + 32, d); d ^= 1; }
  }

  // relu + Ws2 dot partials, row-reduce
  float pr[16];
  #pragma unroll
  for (int g = 0; g < 16; g++) {
    float s = 0.f;
    #pragma unroll
    for (int nf = 0; nf < 2; nf++) {
      const int col = wn * 64 + nf * 32 + lr;
      const float v = fmaxf(acc[nf][g] + bs1[col], 0.f);
      s += v * Ws2[col];
    }
    pr[g] = s;
  }
  #pragma unroll
  for (int g = 0; g < 16; g++)
    #pragma unroll
    for (int i = 1; i <= 16; i <<= 1) pr[g] += __shfl_xor(pr[g], i, 64);
  if (lr == 0) {
    #pragma unroll
    for (int g = 0; g < 16; g++) {
      const int row_l = wm * 32 + (g & 3) + 8 * (g >> 2) + 4 * lg;
      red[row_l][wn] = pr[g];
    }
  }
  __syncthreads();

  // ACT update: thread tid owns column tid for all 64 rows
  const float ipsb = 1.f / (psb[0] + 1e-8f);
  const float pa = psa[0], b2 = bs2[0];
  for (int row_l = 0; row_l < 64; row_l++) {
    const long rg = m0 + row_l;
    const float s = red[row_l][0] + red[row_l][1] + b2;
    const float curv = 1.f / (1.f + expf(-(s - pa) * ipsb));
    const float cu = FIRST ? 0.f : cum[rg];
    const float re = FIRST ? 1.f : rem[rg];
    const float st = FIRST ? 1.f : still[rg];
    const float pp = FIRST ? 0.f : pc[rg];
    const float cum_n = cu + curv * st;
    float pc_n = pp + st;
    const float still_n = (cum_n < 0.9999f) ? 1.f : 0.f;
    const float wgt = curv * still_n + re * (1.f - still_n);
    const long idx = rg * HD + tid;
    const float prev = FIRST ? 0.f : ((float)outhi[idx] + (float)outlo[idx]);
    const float hhv = (float)hhhi[idx] + (float)hhlo[idx];
    const float newv = prev + hhv * wgt;
    const f16 hi = (f16)newv;
    outhi[idx] = hi;
    outlo[idx] = (f16)(newv - (float)hi);
    const float rem_n = re - curv * still_n;
    pc_n += rem_n * (1.f - still_n);
    if (tid == 0) {
      cum[rg] = cum_n; rem[rg] = rem_n; still[rg] = still_n; pc[rg] = pc_n;
      pcdst[rg] = pc_n;
      if (still_n > 0.5f) *myFlag = 1;
    }
  }
}

// ---------------------------------------------------------------------------
// Last-iteration ACT (cur = 1), hi/lo IO. 8 rows per block.
// ---------------------------------------------------------------------------
__global__ __launch_bounds__(256) void act_last(
    const f16* __restrict__ hhhi, const f16* __restrict__ hhlo,
    float* __restrict__ cum, float* __restrict__ rem,
    float* __restrict__ still, float* __restrict__ pc,
    f16* __restrict__ outhi, f16* __restrict__ outlo,
    float* __restrict__ pcdst, const int* __restrict__ alive)
{
  if (alive && *alive == 0) return;
  const int tid = threadIdx.x;
  for (int rr = 0; rr < 8; rr++) {
    const long r = (long)blockIdx.x * 8 + rr;
    const float re = rem[r], st = still[r];
    const float cum_n = cum[r] + st;
    float pc_n = pc[r] + st;
    const float still_n = (cum_n < 0.9999f) ? 1.f : 0.f;
    const float wgt = still_n + re * (1.f - still_n);
    const long idx = r * HD + tid;
    const float newv = (float)outhi[idx] + (float)outlo[idx]
                     + ((float)hhhi[idx] + (float)hhlo[idx]) * wgt;
    const f16 hi = (f16)newv;
    outhi[idx] = hi;
    outlo[idx] = (f16)(newv - (float)hi);
    const float rem_n = re - still_n;
    pc_n += rem_n * (1.f - still_n);
    if (tid == 0) {
      cum[r] = cum_n; rem[r] = rem_n; still[r] = still_n; pc[r] = pc_n;
      pcdst[r] = pc_n;
    }
  }
}

// ---------------------------------------------------------------------------
// Weight transpose + split into packed frag layout (512B chunks).
// ---------------------------------------------------------------------------
__global__ __launch_bounds__(256) void wsplit_k(
    const float* __restrict__ W_in, const float* __restrict__ Wq,
    const float* __restrict__ Wk, const float* __restrict__ Wv,
    const float* __restrict__ Wo, const float* __restrict__ Wf1,
    const float* __restrict__ Wf2, const float* __restrict__ Ws1,
    const float* __restrict__ Wout,
    f16* __restrict__ WinP, f16* __restrict__ WqkvP, f16* __restrict__ WoP,
    f16* __restrict__ Wf1P, f16* __restrict__ Wf2P, f16* __restrict__ Ws1P,
    f16* __restrict__ WoutP)
{
  const int y = blockIdx.y;
  const long idx = (long)blockIdx.x * 256 + threadIdx.x;
  int Npad, Kpad, Ksrc;
  f16* dst;
  switch (y) {
    case 0: Npad = 256; Kpad = 288; Ksrc = 257; dst = WinP;  break;
    case 1: Npad = 768; Kpad = 256; Ksrc = 256; dst = WqkvP; break;
    case 2: Npad = 256; Kpad = 256; Ksrc = 256; dst = WoP;   break;
    case 3: Npad = 512; Kpad = 256; Ksrc = 256; dst = Wf1P;  break;
    case 4: Npad = 256; Kpad = 512; Ksrc = 512; dst = Wf2P;  break;
    case 5: Npad = 128; Kpad = 256; Ksrc = 256; dst = Ws1P;  break;
    default: Npad = 384; Kpad = 256; Ksrc = 256; dst = WoutP; break;
  }
  if (idx >= (long)Npad * Kpad) return;
  const int n = (int)(idx / Kpad), k = (int)(idx % Kpad);
  float v = 0.f;
  if (k < Ksrc) {
    switch (y) {
      case 0: v = W_in[(long)k * 256 + n]; break;
      case 1: { const int sel = n >> 8;
                const float* s = sel == 0 ? Wq : (sel == 1 ? Wk : Wv);
                v = s[(long)k * 256 + (n & 255)]; } break;
      case 2: v = Wo[(long)k * 256 + n]; break;
      case 3: v = Wf1[(long)k * 512 + n]; break;
      case 4: v = Wf2[(long)k * 256 + n]; break;
      case 5: v = Ws1[(long)k * 128 + n]; break;
      default: v = (n < 257) ? Wout[(long)k * 257 + n] : 0.f; break;
    }
  }
  const long base = ((long)(n >> 5) * (Kpad >> 3) + (k >> 3)) * 512 + (n & 31) * 8 + (k & 7);
  const f16 hi = (f16)v;
  dst[base] = hi;
  dst[base + 256] = (f16)(v - (float)hi);
}

// ---------------------------------------------------------------------------
// Per-time-frame attention over channels; writes ctx as f16 hi/lo.
// ---------------------------------------------------------------------------
template<int NCc>
__global__ __launch_bounds__(256) void attn_k(
    const float* __restrict__ Q, const float* __restrict__ Ksp,
    const float* __restrict__ Vsp, f16* __restrict__ chi,
    f16* __restrict__ clo, const int* __restrict__ alive)
{
  if (alive && *alive == 0) return;
  const int w = threadIdx.x >> 6;
  const int l = threadIdx.x & 63;
  for (int rr = 0; rr < 4; rr++) {
    const long r = (long)blockIdx.x * 4 + rr;
    const float qv = Q[r * HD + w * DHD + l];
    float sc[NCc];
    #pragma unroll
    for (int c = 0; c < NCc; c++) {
      float p = qv * Ksp[((long)c * RR + r) * HD + w * DHD + l];
      #pragma unroll
      for (int s = 32; s > 0; s >>= 1) p += __shfl_xor(p, s, 64);
      sc[c] = p * 0.125f;
    }
    float m = sc[0];
    #pragma unroll
    for (int c = 1; c < NCc; c++) m = fmaxf(m, sc[c]);
    float a[NCc];
    float den = 0.f;
    #pragma unroll
    for (int c = 0; c < NCc; c++) { a[c] = expf(sc[c] - m); den += a[c]; }
    float cv = 0.f;
    #pragma unroll
    for (int c = 0; c < NCc; c++)
      cv = fmaf(a[c] / den, Vsp[((long)c * RR + r) * HD + w * DHD + l], cv);
    const f16 hi = (f16)cv;
    chi[r * HD + w * DHD + l] = hi;
    clo[r * HD + w * DHD + l] = (f16)(cv - (float)hi);
  }
}

__global__ void init_k(int* flags) {
  if (threadIdx.x < 8) flags[threadIdx.x] = 0;
}

// ---------------------------------------------------------------------------
extern "C" void kernel_launch(void* const* d_in, const int* in_sizes, int n_in,
                              void* d_out, int out_size, void* d_ws, size_t ws_size,
                              hipStream_t stream) {
  const float* x    = (const float*)d_in[0];
  const float* W_in = (const float*)d_in[1];
  const float* b_in = (const float*)d_in[2];
  const float* W_out= (const float*)d_in[3];
  const float* b_out= (const float*)d_in[4];
  const float* Wq   = (const float*)d_in[5];
  const float* bq   = (const float*)d_in[6];
  const float* Wk   = (const float*)d_in[7];
  const float* bk   = (const float*)d_in[8];
  const float* Wv   = (const float*)d_in[9];
  const float* bv   = (const float*)d_in[10];
  const float* Wo   = (const float*)d_in[11];
  const float* bo   = (const float*)d_in[12];
  const float* ln1g = (const float*)d_in[13];
  const float* ln1b = (const float*)d_in[14];
  const float* Wf1  = (const float*)d_in[15];
  const float* bf1  = (const float*)d_in[16];
  const float* Wf2  = (const float*)d_in[17];
  const float* bf2  = (const float*)d_in[18];
  const float* ln2g = (const float*)d_in[19];
  const float* ln2b = (const float*)d_in[20];
  const float* Ws1  = (const float*)d_in[21];
  const float* bs1  = (const float*)d_in[22];
  const float* Ws2  = (const float*)d_in[23];
  const float* bs2  = (const float*)d_in[24];
  const float* psa  = (const float*)d_in[25];
  const float* psb  = (const float*)d_in[26];

  float* ws = (float*)d_ws;
  long off = 0;
  auto alloc = [&](long n) { float* p = ws + off; off += n; return p; };
  float* Ks   = alloc((long)CH * RR * HD);
  float* Vs   = alloc((long)CH * RR * HD);
  float* Qb   = alloc((long)RR * HD);
  f16* lin1hi = (f16*)alloc((long)RR * HD / 2);
  f16* lin1lo = (f16*)alloc((long)RR * HD / 2);
  f16* ctxhi  = (f16*)alloc((long)RR * HD / 2);
  f16* ctxlo  = (f16*)alloc((long)RR * HD / 2);
  f16* h1hi   = (f16*)alloc((long)RR * HD / 2);
  f16* h1lo   = (f16*)alloc((long)RR * HD / 2);
  f16* hhhi   = (f16*)alloc((long)RR * HD / 2);
  f16* hhlo   = (f16*)alloc((long)RR * HD / 2);
  f16* t1hi   = (f16*)alloc((long)RR * WN / 2);
  f16* t1lo   = (f16*)alloc((long)RR * WN / 2);
  f16* outhi  = (f16*)alloc((long)RR * HD / 2);
  f16* outlo  = (f16*)alloc((long)RR * HD / 2);
  f16* WinP   = (f16*)alloc(2 * 256 * 288 / 2);
  f16* WqkvP  = (f16*)alloc(2 * 768 * 256 / 2);
  f16* WoP    = (f16*)alloc(2 * 256 * 256 / 2);
  f16* Wf1P   = (f16*)alloc(2 * 512 * 256 / 2);
  f16* Wf2P   = (f16*)alloc(2 * 256 * 512 / 2);
  f16* Ws1P   = (f16*)alloc(2 * 128 * 256 / 2);
  f16* WoutP  = (f16*)alloc(2 * 384 * 256 / 2);
  float* cum  = alloc(RR);
  float* rem  = alloc(RR);
  float* still= alloc(RR);
  float* pc   = alloc(RR);
  int* flags  = (int*)alloc(8);

  init_k<<<1, 256, 0, stream>>>(flags);
  wsplit_k<<<dim3(768, 7), 256, 0, stream>>>(
      W_in, Wq, Wk, Wv, Wo, Wf1, Wf2, Ws1, W_out,
      WinP, WqkvP, WoP, Wf1P, Wf2P, Ws1P, WoutP);

  float* pcdst = (float*)d_out + (long)RR * FB;

  for (int ci = 0; ci < CH; ci++) {
    const int* al = (ci == 0) ? nullptr : (flags + ci - 1);
    // lin1 = relu(x[:,ci] @ W_in + b_in) -> hi/lo
    gemm2<1, 0, 1, 0, 1><<<dim3(128, 4), 256, 0, stream>>>(
        nullptr, nullptr, KXP, x + (long)ci * TT * FB, (long)CH * TT * FB,
        WinP, b_in, b_in, b_in, nullptr, nullptr, nullptr, HD,
        lin1hi, lin1lo, HD, HD, al);
    // fused Q/K/V projections (N=768)
    gemm2<0, 1, 0, 1, 0><<<dim3(128, 12), 256, 0, stream>>>(
        lin1hi, lin1lo, HD, nullptr, 0, WqkvP, bq, bk, bv,
        Qb, Ks + (long)ci * RR * HD, Vs + (long)ci * RR * HD, HD,
        nullptr, nullptr, HD, 768, al);
    // attention over channels 0..ci
    switch (ci) {
      case 0: attn_k<1><<<4096, 256, 0, stream>>>(Qb, Ks, Vs, ctxhi, ctxlo, al); break;
      case 1: attn_k<2><<<4096, 256, 0, stream>>>(Qb, Ks, Vs, ctxhi, ctxlo, al); break;
      case 2: attn_k<3><<<4096, 256, 0, stream>>>(Qb, Ks, Vs, ctxhi, ctxlo, al); break;
      case 3: attn_k<4><<<4096, 256, 0, stream>>>(Qb, Ks, Vs, ctxhi, ctxlo, al); break;
      case 4: attn_k<5><<<4096, 256, 0, stream>>>(Qb, Ks, Vs, ctxhi, ctxlo, al); break;
      case 5: attn_k<6><<<4096, 256, 0, stream>>>(Qb, Ks, Vs, ctxhi, ctxlo, al); break;
      case 6: attn_k<7><<<4096, 256, 0, stream>>>(Qb, Ks, Vs, ctxhi, ctxlo, al); break;
      default: attn_k<8><<<4096, 256, 0, stream>>>(Qb, Ks, Vs, ctxhi, ctxlo, al); break;
    }
    // h1 = LN(lin1 + ctx @ Wo + bo)   [FUSED]
    gemm_ln<<<256, 512, 0, stream>>>(
        ctxhi, ctxlo, HD, WoP, bo, lin1hi, lin1lo, ln1g, ln1b,
        h1hi, h1lo, al);
    // t1 = relu(h1 @ Wf1 + bf1)
    gemm2<1, 0, 1, 0, 0><<<dim3(128, 8), 256, 0, stream>>>(
        h1hi, h1lo, HD, nullptr, 0, Wf1P, bf1, bf1, bf1,
        nullptr, nullptr, nullptr, WN, t1hi, t1lo, WN, WN, al);
    // hh = LN(h1 + t1 @ Wf2 + bf2)   [FUSED]
    gemm_ln<<<256, 512, 0, stream>>>(
        t1hi, t1lo, WN, Wf2P, bf2, h1hi, h1lo, ln2g, ln2b,
        hhhi, hhlo, al);
    // ponder head + ACT update [FUSED] (last iter: cur = 1)
    if (ci == 0)
      s1_act<1><<<256, 256, 0, stream>>>(
          hhhi, hhlo, Ws1P, bs1, Ws2, bs2, psa, psb,
          cum, rem, still, pc, outhi, outlo, pcdst, nullptr, flags + 0);
    else if (ci < CH - 1)
      s1_act<0><<<256, 256, 0, stream>>>(
          hhhi, hhlo, Ws1P, bs1, Ws2, bs2, psa, psb,
          cum, rem, still, pc, outhi, outlo, pcdst, al, flags + ci);
    else
      act_last<<<2048, 256, 0, stream>>>(
          hhhi, hhlo, cum, rem, still, pc, outhi, outlo, pcdst, al);
  }
  // encoder_out = relu(out @ W_out + b_out)
  gemm2<1, 1, 0, 0, 0><<<dim3(128, 6), 256, 0, stream>>>(
      outhi, outlo, HD, nullptr, 0, WoutP, b_out, b_out, b_out,
      (float*)d_out, nullptr, nullptr, FB, nullptr, nullptr, HD, FB, nullptr);
}

// Round 8
// 749.736 us; speedup vs baseline: 1.3444x; 1.1384x over previous
//
#include <hip/hip_runtime.h>
#include <hip/hip_bf16.h>
#include <math.h>

typedef _Float16 f16;
typedef _Float16 f16x4 __attribute__((ext_vector_type(4)));
typedef _Float16 f16x8 __attribute__((ext_vector_type(8)));
typedef float f32x16 __attribute__((ext_vector_type(16)));

constexpr int CH = 8;      // channels
constexpr int TT = 2048;   // time frames
constexpr int FB = 257;    // freq bins
constexpr int HD = 256;    // hidden
constexpr int DHD = 64;    // head dim
constexpr int WN = 512;    // ffn dim
constexpr int HF = 128;    // H/2
constexpr int RR = 8 * TT; // 16384 rows
constexpr int KXP = 288;   // padded K for x / W_in

// ===========================================================================
// MFMA triple helper: acc += (Ah+Al) * (Bh+Bl) to ~2^-22 rel:
//   acc = Al*Bh + Ah*Bl + Ah*Bh
#define MFMA3(ACCV, AH, AL, BH, BL)                                            \
  ACCV = __builtin_amdgcn_mfma_f32_32x32x16_f16(AL, BH, ACCV, 0, 0, 0);        \
  ACCV = __builtin_amdgcn_mfma_f32_32x32x16_f16(AH, BL, ACCV, 0, 0, 0);        \
  ACCV = __builtin_amdgcn_mfma_f32_32x32x16_f16(AH, BH, ACCV, 0, 0, 0);

// ---------------------------------------------------------------------------
// gemm2 (R5-best, used only for final W_out GEMM): tile 128x64, 4 waves.
// ---------------------------------------------------------------------------
template<int ACT>
__global__ __launch_bounds__(256, 2) void gemm2(
    const f16* __restrict__ Ahi, const f16* __restrict__ Alo, int K,
    const f16* __restrict__ Bp, const float* __restrict__ bias,
    float* __restrict__ C0, int ldc, int Nreal)
{
  __shared__ f16 As[2][2][128][40];
  const int tid = threadIdx.x;
  const int m0 = blockIdx.x * 128;
  const int n0 = blockIdx.y * 64;
  const int q = tid & 3, r = tid >> 2;
  const int lane = tid & 63, wm = tid >> 6;
  const int lr = lane & 31, lg = lane >> 5;
  const int nb0 = n0 >> 5, kd8 = K >> 3;

  f32x16 acc[2];
  #pragma unroll
  for (int nf = 0; nf < 2; nf++)
    #pragma unroll
    for (int g = 0; g < 16; g++) acc[nf][g] = 0.f;

  const long aoff = (long)(m0 + r) * K + q * 8;
  const long hstep = (long)64 * K;
  f16x8 sA[4];
  auto loadA = [&](int k0) {
    const long a = aoff + k0;
    sA[0] = *(const f16x8*)(Ahi + a);  sA[1] = *(const f16x8*)(Ahi + a + hstep);
    sA[2] = *(const f16x8*)(Alo + a);  sA[3] = *(const f16x8*)(Alo + a + hstep);
  };
  auto loadB = [&](f16x8 B[2][2][2], int k0) {
    const int kb = (k0 >> 3) + lg;
    #pragma unroll
    for (int kh = 0; kh < 2; kh++)
      #pragma unroll
      for (int nf = 0; nf < 2; nf++)
        #pragma unroll
        for (int hl = 0; hl < 2; hl++)
          B[kh][nf][hl] = *(const f16x8*)(Bp +
              ((long)((nb0 + nf) * kd8 + kb + kh * 2) * 512 + hl * 256 + lr * 8));
  };
  auto kstep = [&](f16x8 SB[2][2][2], f16x8 TB[2][2][2], int k0, int d) {
    *(f16x8*)&As[d][0][r][q * 8]      = sA[0];
    *(f16x8*)&As[d][0][r + 64][q * 8] = sA[1];
    *(f16x8*)&As[d][1][r][q * 8]      = sA[2];
    *(f16x8*)&As[d][1][r + 64][q * 8] = sA[3];
    __syncthreads();
    if (k0 + 32 < K) { loadA(k0 + 32); loadB(TB, k0 + 32); }
    f16x8 fa[2][2];
    #pragma unroll
    for (int kh = 0; kh < 2; kh++)
      #pragma unroll
      for (int hl = 0; hl < 2; hl++)
        fa[kh][hl] = *(const f16x8*)&As[d][hl][wm * 32 + lr][kh * 16 + lg * 8];
    #pragma unroll
    for (int kh = 0; kh < 2; kh++)
      #pragma unroll
      for (int nf = 0; nf < 2; nf++) {
        MFMA3(acc[nf], fa[kh][0], fa[kh][1], SB[kh][nf][0], SB[kh][nf][1]);
      }
  };

  f16x8 B0[2][2][2], B1[2][2][2];
  loadA(0);
  loadB(B0, 0);
  int d = 0;
  for (int k0 = 0; k0 < K; k0 += 64) {
    kstep(B0, B1, k0, d); d ^= 1;
    if (k0 + 32 < K) { kstep(B1, B0, k0 + 32, d); d ^= 1; }
  }

  #pragma unroll
  for (int nf = 0; nf < 2; nf++) {
    const int col = n0 + nf * 32 + lr;
    const float bb = (col < Nreal) ? bias[col] : 0.f;
    #pragma unroll
    for (int g = 0; g < 16; g++) {
      const long row = m0 + wm * 32 + (g & 3) + 8 * (g >> 2) + 4 * lg;
      float v = acc[nf][g] + bb;
      if (ACT) v = fmaxf(v, 0.f);
      if (col < Nreal) C0[row * (long)ldc + col] = v;
    }
  }
}

// ---------------------------------------------------------------------------
// FUSED lin1 + QKV: per 64-row block:
//   lin1 = relu(x @ W_in + b_in)   (K=288, x fp32 split on the fly)
//   -> LDS (hi/lo) + global lin1hi/lo (residual for LN1)
//   Q/K/V = lin1 @ {Wq,Wk,Wv} + b   (3x N=256, K=256, A from LDS)
// 512 thr = 8 waves (2 wm x 4 wn), wave tile 32x64.
// ---------------------------------------------------------------------------
__global__ __launch_bounds__(512) void lin1_qkv(
    const float* __restrict__ x, long agrp,
    const f16* __restrict__ WinP, const float* __restrict__ b_in,
    const f16* __restrict__ WqkvP, const float* __restrict__ bq,
    const float* __restrict__ bk, const float* __restrict__ bv,
    f16* __restrict__ lin1hi, f16* __restrict__ lin1lo,
    float* __restrict__ Qb, float* __restrict__ Ksd, float* __restrict__ Vsd,
    const int* __restrict__ alive)
{
  if (alive && *alive == 0) return;
  __shared__ f16 As[2][2][64][40];   // x staging dbuf
  __shared__ f16 L1[2][64][264];     // lin1 hi/lo, full K (264: 16B-aligned rows)
  const int tid = threadIdx.x;
  const int m0 = blockIdx.x * 64;
  const int lane = tid & 63, wave = tid >> 6;
  const int wm = wave & 1, wn = wave >> 1;
  const int lr = lane & 31, lg = lane >> 5;
  const int srow = tid >> 3, sk = (tid & 7) * 4;

  const int r0 = m0 + srow;
  const float* xrow = x + (long)(r0 >> 11) * agrp + (long)(r0 & 2047) * FB;

  f16x4 sAh, sAl;
  auto loadA = [&](int k0) {
    float v[4];
    #pragma unroll
    for (int j = 0; j < 4; j++) {
      const int k = k0 + sk + j;
      v[j] = (k < FB) ? xrow[k] : 0.f;
    }
    #pragma unroll
    for (int j = 0; j < 4; j++) {
      const f16 h = (f16)v[j];
      sAh[j] = h; sAl[j] = (f16)(v[j] - (float)h);
    }
  };
  auto loadB1 = [&](f16x8 B[2][2][2], int k0) {
    const int kb = (k0 >> 3) + lg;
    #pragma unroll
    for (int kh = 0; kh < 2; kh++)
      #pragma unroll
      for (int nf = 0; nf < 2; nf++)
        #pragma unroll
        for (int hl = 0; hl < 2; hl++)
          B[kh][nf][hl] = *(const f16x8*)(WinP +
              ((long)((wn * 2 + nf) * 36 + kb + kh * 2) * 512 + hl * 256 + lr * 8));
  };

  f32x16 acc[2];
  #pragma unroll
  for (int nf = 0; nf < 2; nf++)
    #pragma unroll
    for (int g = 0; g < 16; g++) acc[nf][g] = 0.f;

  auto kstep1 = [&](f16x8 SB[2][2][2], f16x8 TB[2][2][2], int k0, int d) {
    *(f16x4*)&As[d][0][srow][sk] = sAh;
    *(f16x4*)&As[d][1][srow][sk] = sAl;
    __syncthreads();
    if (k0 + 32 < KXP) { loadA(k0 + 32); loadB1(TB, k0 + 32); }
    f16x8 fa[2][2];
    #pragma unroll
    for (int kh = 0; kh < 2; kh++)
      #pragma unroll
      for (int hl = 0; hl < 2; hl++)
        fa[kh][hl] = *(const f16x8*)&As[d][hl][wm * 32 + lr][kh * 16 + lg * 8];
    #pragma unroll
    for (int kh = 0; kh < 2; kh++)
      #pragma unroll
      for (int nf = 0; nf < 2; nf++) {
        MFMA3(acc[nf], fa[kh][0], fa[kh][1], SB[kh][nf][0], SB[kh][nf][1]);
      }
  };

  f16x8 B0[2][2][2], B1[2][2][2];
  loadA(0);
  loadB1(B0, 0);
  #pragma unroll
  for (int s = 0; s < 9; s++) {     // KXP/32 = 9
    if ((s & 1) == 0) kstep1(B0, B1, s * 32, 0);
    else              kstep1(B1, B0, s * 32, 1);
  }

  // epilogue phase 1: relu+bias -> L1 LDS + global lin1
  #pragma unroll
  for (int nf = 0; nf < 2; nf++) {
    const int col = wn * 64 + nf * 32 + lr;
    const float bb = b_in[col];
    #pragma unroll
    for (int g = 0; g < 16; g++) {
      const int row_l = wm * 32 + (g & 3) + 8 * (g >> 2) + 4 * lg;
      const float v = fmaxf(acc[nf][g] + bb, 0.f);
      const f16 hi = (f16)v;
      const f16 lo = (f16)(v - (float)hi);
      L1[0][row_l][col] = hi;
      L1[1][row_l][col] = lo;
      const long gi = (long)(m0 + row_l) * HD + col;
      lin1hi[gi] = hi;
      lin1lo[gi] = lo;
    }
  }
  __syncthreads();

  // phase 2: Q/K/V from L1
  auto loadB2 = [&](f16x8 B[2][2][2], int k0, int sel) {
    const int kb = (k0 >> 3) + lg;
    #pragma unroll
    for (int kh = 0; kh < 2; kh++)
      #pragma unroll
      for (int nf = 0; nf < 2; nf++)
        #pragma unroll
        for (int hl = 0; hl < 2; hl++)
          B[kh][nf][hl] = *(const f16x8*)(WqkvP +
              ((long)((sel * 8 + wn * 2 + nf) * 32 + kb + kh * 2) * 512 + hl * 256 + lr * 8));
  };
  #pragma unroll
  for (int sel = 0; sel < 3; sel++) {
    f32x16 a2[2];
    #pragma unroll
    for (int nf = 0; nf < 2; nf++)
      #pragma unroll
      for (int g = 0; g < 16; g++) a2[nf][g] = 0.f;
    f16x8 Bc[2][2][2], Bn[2][2][2];
    loadB2(Bc, 0, sel);
    #pragma unroll
    for (int s = 0; s < 8; s++) {    // K=256
      const int k0 = s * 32;
      if (s < 7) loadB2((s & 1) ? Bc : Bn, k0 + 32, sel);
      f16x8 fa[2][2];
      #pragma unroll
      for (int kh = 0; kh < 2; kh++)
        #pragma unroll
        for (int hl = 0; hl < 2; hl++)
          fa[kh][hl] = *(const f16x8*)&L1[hl][wm * 32 + lr][k0 + kh * 16 + lg * 8];
      #pragma unroll
      for (int kh = 0; kh < 2; kh++)
        #pragma unroll
        for (int nf = 0; nf < 2; nf++) {
          if (s & 1) { MFMA3(a2[nf], fa[kh][0], fa[kh][1], Bn[kh][nf][0], Bn[kh][nf][1]); }
          else       { MFMA3(a2[nf], fa[kh][0], fa[kh][1], Bc[kh][nf][0], Bc[kh][nf][1]); }
        }
    }
    float* dst = sel == 0 ? Qb : (sel == 1 ? Ksd : Vsd);
    const float* bp = sel == 0 ? bq : (sel == 1 ? bk : bv);
    #pragma unroll
    for (int nf = 0; nf < 2; nf++) {
      const int col = wn * 64 + nf * 32 + lr;
      const float bb = bp[col];
      #pragma unroll
      for (int g = 0; g < 16; g++) {
        const int row_l = wm * 32 + (g & 3) + 8 * (g >> 2) + 4 * lg;
        dst[(long)(m0 + row_l) * HD + col] = a2[nf][g] + bb;
      }
    }
  }
}

// ---------------------------------------------------------------------------
// FUSED FFN: hh = LN(h1 + relu(h1@Wf1+bf1)@Wf2 + bf2).
// h1 staged to LDS once; t1 computed per 256-col half into LDS; second GEMM
// accumulates across halves (ascending k order == unfused bitwise).
// 512 thr = 8 waves (2 wm x 4 wn), wave tile 32x64. LDS ~137 KB.
// ---------------------------------------------------------------------------
__global__ __launch_bounds__(512) void ffn_ln(
    const f16* __restrict__ h1hi, const f16* __restrict__ h1lo,
    const f16* __restrict__ Wf1P, const float* __restrict__ bf1,
    const f16* __restrict__ Wf2P, const float* __restrict__ bf2,
    const float* __restrict__ g2, const float* __restrict__ b2,
    f16* __restrict__ hhhi, f16* __restrict__ hhlo,
    const int* __restrict__ alive)
{
  if (alive && *alive == 0) return;
  __shared__ f16 H1[2][64][264];
  __shared__ f16 T1[2][64][264];
  __shared__ float red[64][4][2];
  const int tid = threadIdx.x;
  const int m0 = blockIdx.x * 64;
  const int lane = tid & 63, wave = tid >> 6;
  const int wm = wave & 1, wn = wave >> 1;
  const int lr = lane & 31, lg = lane >> 5;

  // cooperative load h1 -> H1
  {
    const int srow = tid >> 3, scg = (tid & 7) * 32;
    const long hb = (long)(m0 + srow) * HD + scg;
    #pragma unroll
    for (int j = 0; j < 4; j++) {
      *(f16x8*)&H1[0][srow][scg + j * 8] = *(const f16x8*)(h1hi + hb + j * 8);
      *(f16x8*)&H1[1][srow][scg + j * 8] = *(const f16x8*)(h1lo + hb + j * 8);
    }
  }
  __syncthreads();

  auto loadBf1 = [&](f16x8 B[2][2][2], int k0, int p) {
    const int kb = (k0 >> 3) + lg;
    #pragma unroll
    for (int kh = 0; kh < 2; kh++)
      #pragma unroll
      for (int nf = 0; nf < 2; nf++)
        #pragma unroll
        for (int hl = 0; hl < 2; hl++)
          B[kh][nf][hl] = *(const f16x8*)(Wf1P +
              ((long)((p * 8 + wn * 2 + nf) * 32 + kb + kh * 2) * 512 + hl * 256 + lr * 8));
  };
  auto loadBf2 = [&](f16x8 B[2][2][2], int k0, int p) {
    const int kb = p * 32 + (k0 >> 3) + lg;
    #pragma unroll
    for (int kh = 0; kh < 2; kh++)
      #pragma unroll
      for (int nf = 0; nf < 2; nf++)
        #pragma unroll
        for (int hl = 0; hl < 2; hl++)
          B[kh][nf][hl] = *(const f16x8*)(Wf2P +
              ((long)((wn * 2 + nf) * 64 + kb + kh * 2) * 512 + hl * 256 + lr * 8));
  };

  f32x16 hacc[2];
  #pragma unroll
  for (int nf = 0; nf < 2; nf++)
    #pragma unroll
    for (int g = 0; g < 16; g++) hacc[nf][g] = 0.f;

  #pragma unroll
  for (int p = 0; p < 2; p++) {
    // GEMM1: ta = h1 @ Wf1[:, p*256 + *]
    f32x16 ta[2];
    #pragma unroll
    for (int nf = 0; nf < 2; nf++)
      #pragma unroll
      for (int g = 0; g < 16; g++) ta[nf][g] = 0.f;
    {
      f16x8 Bc[2][2][2], Bn[2][2][2];
      loadBf1(Bc, 0, p);
      #pragma unroll
      for (int s = 0; s < 8; s++) {
        const int k0 = s * 32;
        if (s < 7) loadBf1((s & 1) ? Bc : Bn, k0 + 32, p);
        f16x8 fa[2][2];
        #pragma unroll
        for (int kh = 0; kh < 2; kh++)
          #pragma unroll
          for (int hl = 0; hl < 2; hl++)
            fa[kh][hl] = *(const f16x8*)&H1[hl][wm * 32 + lr][k0 + kh * 16 + lg * 8];
        #pragma unroll
        for (int kh = 0; kh < 2; kh++)
          #pragma unroll
          for (int nf = 0; nf < 2; nf++) {
            if (s & 1) { MFMA3(ta[nf], fa[kh][0], fa[kh][1], Bn[kh][nf][0], Bn[kh][nf][1]); }
            else       { MFMA3(ta[nf], fa[kh][0], fa[kh][1], Bc[kh][nf][0], Bc[kh][nf][1]); }
          }
      }
    }
    __syncthreads();   // prior T1 readers done
    // relu + bias -> T1
    #pragma unroll
    for (int nf = 0; nf < 2; nf++) {
      const int col = wn * 64 + nf * 32 + lr;
      const float bb = bf1[p * 256 + col];
      #pragma unroll
      for (int g = 0; g < 16; g++) {
        const int row_l = wm * 32 + (g & 3) + 8 * (g >> 2) + 4 * lg;
        const float v = fmaxf(ta[nf][g] + bb, 0.f);
        const f16 hi = (f16)v;
        T1[0][row_l][col] = hi;
        T1[1][row_l][col] = (f16)(v - (float)hi);
      }
    }
    __syncthreads();
    // GEMM2: hacc += T1 @ Wf2[p*256 + *, :]
    {
      f16x8 Bc[2][2][2], Bn[2][2][2];
      loadBf2(Bc, 0, p);
      #pragma unroll
      for (int s = 0; s < 8; s++) {
        const int k0 = s * 32;
        if (s < 7) loadBf2((s & 1) ? Bc : Bn, k0 + 32, p);
        f16x8 ft[2][2];
        #pragma unroll
        for (int kh = 0; kh < 2; kh++)
          #pragma unroll
          for (int hl = 0; hl < 2; hl++)
            ft[kh][hl] = *(const f16x8*)&T1[hl][wm * 32 + lr][k0 + kh * 16 + lg * 8];
        #pragma unroll
        for (int kh = 0; kh < 2; kh++)
          #pragma unroll
          for (int nf = 0; nf < 2; nf++) {
            if (s & 1) { MFMA3(hacc[nf], ft[kh][0], ft[kh][1], Bn[kh][nf][0], Bn[kh][nf][1]); }
            else       { MFMA3(hacc[nf], ft[kh][0], ft[kh][1], Bc[kh][nf][0], Bc[kh][nf][1]); }
          }
      }
    }
  }

  // LN epilogue: v = hacc + bf2 + h1 (from LDS); LN over 256 cols
  float pr[16], qr[16];
  #pragma unroll
  for (int g = 0; g < 16; g++) {
    const int row_l = wm * 32 + (g & 3) + 8 * (g >> 2) + 4 * lg;
    float s = 0.f, sq = 0.f;
    #pragma unroll
    for (int nf = 0; nf < 2; nf++) {
      const int col = wn * 64 + nf * 32 + lr;
      float v = hacc[nf][g] + bf2[col]
              + (float)H1[0][row_l][col] + (float)H1[1][row_l][col];
      hacc[nf][g] = v;
      s += v; sq += v * v;
    }
    pr[g] = s; qr[g] = sq;
  }
  #pragma unroll
  for (int g = 0; g < 16; g++)
    #pragma unroll
    for (int i = 1; i <= 16; i <<= 1) {
      pr[g] += __shfl_xor(pr[g], i, 64);
      qr[g] += __shfl_xor(qr[g], i, 64);
    }
  if (lr == 0) {
    #pragma unroll
    for (int g = 0; g < 16; g++) {
      const int row_l = wm * 32 + (g & 3) + 8 * (g >> 2) + 4 * lg;
      red[row_l][wn][0] = pr[g];
      red[row_l][wn][1] = qr[g];
    }
  }
  __syncthreads();
  #pragma unroll
  for (int g = 0; g < 16; g++) {
    const int row_l = wm * 32 + (g & 3) + 8 * (g >> 2) + 4 * lg;
    const float mean = (red[row_l][0][0] + red[row_l][1][0] +
                        red[row_l][2][0] + red[row_l][3][0]) * (1.f / HD);
    const float ex2 = (red[row_l][0][1] + red[row_l][1][1] +
                       red[row_l][2][1] + red[row_l][3][1]) * (1.f / HD);
    const float inv = 1.f / sqrtf(ex2 - mean * mean + 1e-5f);
    const long rbase = (long)(m0 + row_l) * HD;
    #pragma unroll
    for (int nf = 0; nf < 2; nf++) {
      const int col = wn * 64 + nf * 32 + lr;
      const float o = (hacc[nf][g] - mean) * inv * g2[col] + b2[col];
      const f16 hi = (f16)o;
      hhhi[rbase + col] = hi;
      hhlo[rbase + col] = (f16)(o - (float)hi);
    }
  }
}

// ---------------------------------------------------------------------------
// FUSED: O(hi/lo) = LN(R + A@W + bias). (R7-verified, unchanged)
// ---------------------------------------------------------------------------
__global__ __launch_bounds__(512) void gemm_ln(
    const f16* __restrict__ Ahi, const f16* __restrict__ Alo, int K,
    const f16* __restrict__ Bp, const float* __restrict__ bias,
    const f16* __restrict__ Rhi, const f16* __restrict__ Rlo,
    const float* __restrict__ gg, const float* __restrict__ bb_,
    f16* __restrict__ Ohi, f16* __restrict__ Olo,
    const int* __restrict__ alive)
{
  if (alive && *alive == 0) return;
  __shared__ f16 As[2][2][64][40];
  __shared__ float red[64][4][2];
  const int tid = threadIdx.x;
  const int m0 = blockIdx.x * 64;
  const int lane = tid & 63, wave = tid >> 6;
  const int wm = wave & 1, wn = wave >> 1;
  const int lr = lane & 31, lg = lane >> 5;
  const int srow = tid >> 3, sk = (tid & 7) * 4;
  const int kd8 = K >> 3;

  f32x16 acc[2];
  #pragma unroll
  for (int nf = 0; nf < 2; nf++)
    #pragma unroll
    for (int g = 0; g < 16; g++) acc[nf][g] = 0.f;

  const f16* arh = Ahi + (long)(m0 + srow) * K + sk;
  const f16* arl = Alo + (long)(m0 + srow) * K + sk;
  f16x4 sAh, sAl;
  auto loadA = [&](int k0) {
    sAh = *(const f16x4*)(arh + k0);
    sAl = *(const f16x4*)(arl + k0);
  };
  auto loadB = [&](f16x8 B[2][2][2], int k0) {
    const int kb = (k0 >> 3) + lg;
    #pragma unroll
    for (int kh = 0; kh < 2; kh++)
      #pragma unroll
      for (int nf = 0; nf < 2; nf++)
        #pragma unroll
        for (int hl = 0; hl < 2; hl++)
          B[kh][nf][hl] = *(const f16x8*)(Bp +
              ((long)((wn * 2 + nf) * kd8 + kb + kh * 2) * 512 + hl * 256 + lr * 8));
  };
  auto kstep = [&](f16x8 SB[2][2][2], f16x8 TB[2][2][2], int k0, int d) {
    *(f16x4*)&As[d][0][srow][sk] = sAh;
    *(f16x4*)&As[d][1][srow][sk] = sAl;
    __syncthreads();
    if (k0 + 32 < K) { loadA(k0 + 32); loadB(TB, k0 + 32); }
    f16x8 fa[2][2];
    #pragma unroll
    for (int kh = 0; kh < 2; kh++)
      #pragma unroll
      for (int hl = 0; hl < 2; hl++)
        fa[kh][hl] = *(const f16x8*)&As[d][hl][wm * 32 + lr][kh * 16 + lg * 8];
    #pragma unroll
    for (int kh = 0; kh < 2; kh++)
      #pragma unroll
      for (int nf = 0; nf < 2; nf++) {
        MFMA3(acc[nf], fa[kh][0], fa[kh][1], SB[kh][nf][0], SB[kh][nf][1]);
      }
  };

  f16x8 B0[2][2][2], B1[2][2][2];
  loadA(0);
  loadB(B0, 0);
  int d = 0;
  for (int k0 = 0; k0 < K; k0 += 64) {
    kstep(B0, B1, k0, d); d ^= 1;
    if (k0 + 32 < K) { kstep(B1, B0, k0 + 32, d); d ^= 1; }
  }

  float pr[16], qr[16];
  #pragma unroll
  for (int g = 0; g < 16; g++) {
    const int row_l = wm * 32 + (g & 3) + 8 * (g >> 2) + 4 * lg;
    const long rbase = (long)(m0 + row_l) * HD;
    float s = 0.f, sq = 0.f;
    #pragma unroll
    for (int nf = 0; nf < 2; nf++) {
      const int col = wn * 64 + nf * 32 + lr;
      float v = acc[nf][g] + bias[col]
              + (float)Rhi[rbase + col] + (float)Rlo[rbase + col];
      acc[nf][g] = v;
      s += v; sq += v * v;
    }
    pr[g] = s; qr[g] = sq;
  }
  #pragma unroll
  for (int g = 0; g < 16; g++)
    #pragma unroll
    for (int i = 1; i <= 16; i <<= 1) {
      pr[g] += __shfl_xor(pr[g], i, 64);
      qr[g] += __shfl_xor(qr[g], i, 64);
    }
  if (lr == 0) {
    #pragma unroll
    for (int g = 0; g < 16; g++) {
      const int row_l = wm * 32 + (g & 3) + 8 * (g >> 2) + 4 * lg;
      red[row_l][wn][0] = pr[g];
      red[row_l][wn][1] = qr[g];
    }
  }
  __syncthreads();
  #pragma unroll
  for (int g = 0; g < 16; g++) {
    const int row_l = wm * 32 + (g & 3) + 8 * (g >> 2) + 4 * lg;
    const float mean = (red[row_l][0][0] + red[row_l][1][0] +
                        red[row_l][2][0] + red[row_l][3][0]) * (1.f / HD);
    const float ex2 = (red[row_l][0][1] + red[row_l][1][1] +
                       red[row_l][2][1] + red[row_l][3][1]) * (1.f / HD);
    const float inv = 1.f / sqrtf(ex2 - mean * mean + 1e-5f);
    const long rbase = (long)(m0 + row_l) * HD;
    #pragma unroll
    for (int nf = 0; nf < 2; nf++) {
      const int col = wn * 64 + nf * 32 + lr;
      const float o = (acc[nf][g] - mean) * inv * gg[col] + bb_[col];
      const f16 hi = (f16)o;
      Ohi[rbase + col] = hi;
      Olo[rbase + col] = (f16)(o - (float)hi);
    }
  }
}

// ---------------------------------------------------------------------------
// FUSED ponder head + ACT update (R7-verified, unchanged).
// ---------------------------------------------------------------------------
template<int FIRST>
__global__ __launch_bounds__(256) void s1_act(
    const f16* __restrict__ hhhi, const f16* __restrict__ hhlo,
    const f16* __restrict__ Bp, const float* __restrict__ bs1,
    const float* __restrict__ Ws2, const float* __restrict__ bs2,
    const float* __restrict__ psa, const float* __restrict__ psb,
    float* __restrict__ cum, float* __restrict__ rem,
    float* __restrict__ still, float* __restrict__ pc,
    f16* __restrict__ outhi, f16* __restrict__ outlo,
    float* __restrict__ pcdst,
    const int* __restrict__ alive, int* __restrict__ myFlag)
{
  if (!FIRST && alive && *alive == 0) return;
  __shared__ f16 As[2][2][64][40];
  __shared__ float red[64][2];
  const int tid = threadIdx.x;
  const int m0 = blockIdx.x * 64;
  const int lane = tid & 63, wave = tid >> 6;
  const int wm = wave & 1, wn = wave >> 1;
  const int lr = lane & 31, lg = lane >> 5;
  const int srow = tid >> 2, sk = (tid & 3) * 8;
  const int K = HD, kd8 = K >> 3;

  f32x16 acc[2];
  #pragma unroll
  for (int nf = 0; nf < 2; nf++)
    #pragma unroll
    for (int g = 0; g < 16; g++) acc[nf][g] = 0.f;

  const f16* arh = hhhi + (long)(m0 + srow) * K + sk;
  const f16* arl = hhlo + (long)(m0 + srow) * K + sk;
  f16x8 sAh, sAl;
  auto loadA = [&](int k0) {
    sAh = *(const f16x8*)(arh + k0);
    sAl = *(const f16x8*)(arl + k0);
  };
  auto loadB = [&](f16x8 B[2][2][2], int k0) {
    const int kb = (k0 >> 3) + lg;
    #pragma unroll
    for (int kh = 0; kh < 2; kh++)
      #pragma unroll
      for (int nf = 0; nf < 2; nf++)
        #pragma unroll
        for (int hl = 0; hl < 2; hl++)
          B[kh][nf][hl] = *(const f16x8*)(Bp +
              ((long)((wn * 2 + nf) * kd8 + kb + kh * 2) * 512 + hl * 256 + lr * 8));
  };
  auto kstep = [&](f16x8 SB[2][2][2], f16x8 TB[2][2][2], int k0, int d) {
    *(f16x8*)&As[d][0][srow][sk] = sAh;
    *(f16x8*)&As[d][1][srow][sk] = sAl;
    __syncthreads();
    if (k0 + 32 < K) { loadA(k0 + 32); loadB(TB, k0 + 32); }
    f16x8 fa[2][2];
    #pragma unroll
    for (int kh = 0; kh < 2; kh++)
      #pragma unroll
      for (int hl = 0; hl < 2; hl++)
        fa[kh][hl] = *(const f16x8*)&As[d][hl][wm * 32 + lr][kh * 16 + lg * 8];
    #pragma unroll
    for (int kh = 0; kh < 2; kh++)
      #pragma unroll
      for (int nf = 0; nf < 2; nf++) {
        MFMA3(acc[nf], fa[kh][0], fa[kh][1], SB[kh][nf][0], SB[kh][nf][1]);
      }
  };

  f16x8 B0[2][2][2], B1[2][2][2];
  loadA(0);
  loadB(B0, 0);
  int d = 0;
  for (int k0 = 0; k0 < K; k0 += 64) {
    kstep(B0, B1, k0, d); d ^= 1;
    if (k0 + 32 < K) { kstep(B1, B0, k0 + 32, d); d ^= 1; }
  }

  float pr[16];
  #pragma unroll
  for (int g = 0; g < 16; g++) {
    float s = 0.f;
    #pragma unroll
    for (int nf = 0; nf < 2; nf++) {
      const int col = wn * 64 + nf * 32 + lr;
      const float v = fmaxf(acc[nf][g] + bs1[col], 0.f);
      s += v * Ws2[col];
    }
    pr[g] = s;
  }
  #pragma unroll
  for (int g = 0; g < 16; g++)
    #pragma unroll
    for (int i = 1; i <= 16; i <<= 1) pr[g] += __shfl_xor(pr[g], i, 64);
  if (lr == 0) {
    #pragma unroll
    for (int g = 0; g < 16; g++) {
      const int row_l = wm * 32 + (g & 3) + 8 * (g >> 2) + 4 * lg;
      red[row_l][wn] = pr[g];
    }
  }
  __syncthreads();

  const float ipsb = 1.f / (psb[0] + 1e-8f);
  const float pa = psa[0], b2v = bs2[0];
  for (int row_l = 0; row_l < 64; row_l++) {
    const long rg = m0 + row_l;
    const float s = red[row_l][0] + red[row_l][1] + b2v;
    const float curv = 1.f / (1.f + expf(-(s - pa) * ipsb));
    const float cu = FIRST ? 0.f : cum[rg];
    const float re = FIRST ? 1.f : rem[rg];
    const float st = FIRST ? 1.f : still[rg];
    const float pp = FIRST ? 0.f : pc[rg];
    const float cum_n = cu + curv * st;
    float pc_n = pp + st;
    const float still_n = (cum_n < 0.9999f) ? 1.f : 0.f;
    const float wgt = curv * still_n + re * (1.f - still_n);
    const long idx = rg * HD + tid;
    const float prev = FIRST ? 0.f : ((float)outhi[idx] + (float)outlo[idx]);
    const float hhv = (float)hhhi[idx] + (float)hhlo[idx];
    const float newv = prev + hhv * wgt;
    const f16 hi = (f16)newv;
    outhi[idx] = hi;
    outlo[idx] = (f16)(newv - (float)hi);
    const float rem_n = re - curv * still_n;
    pc_n += rem_n * (1.f - still_n);
    if (tid == 0) {
      cum[rg] = cum_n; rem[rg] = rem_n; still[rg] = still_n; pc[rg] = pc_n;
      pcdst[rg] = pc_n;
      if (still_n > 0.5f) *myFlag = 1;
    }
  }
}

// ---------------------------------------------------------------------------
// Last-iteration ACT (cur = 1). (R7-verified, unchanged)
// ---------------------------------------------------------------------------
__global__ __launch_bounds__(256) void act_last(
    const f16* __restrict__ hhhi, const f16* __restrict__ hhlo,
    float* __restrict__ cum, float* __restrict__ rem,
    float* __restrict__ still, float* __restrict__ pc,
    f16* __restrict__ outhi, f16* __restrict__ outlo,
    float* __restrict__ pcdst, const int* __restrict__ alive)
{
  if (alive && *alive == 0) return;
  const int tid = threadIdx.x;
  for (int rr = 0; rr < 8; rr++) {
    const long r = (long)blockIdx.x * 8 + rr;
    const float re = rem[r], st = still[r];
    const float cum_n = cum[r] + st;
    float pc_n = pc[r] + st;
    const float still_n = (cum_n < 0.9999f) ? 1.f : 0.f;
    const float wgt = still_n + re * (1.f - still_n);
    const long idx = r * HD + tid;
    const float newv = (float)outhi[idx] + (float)outlo[idx]
                     + ((float)hhhi[idx] + (float)hhlo[idx]) * wgt;
    const f16 hi = (f16)newv;
    outhi[idx] = hi;
    outlo[idx] = (f16)(newv - (float)hi);
    const float rem_n = re - still_n;
    pc_n += rem_n * (1.f - still_n);
    if (tid == 0) {
      cum[r] = cum_n; rem[r] = rem_n; still[r] = still_n; pc[r] = pc_n;
      pcdst[r] = pc_n;
    }
  }
}

// ---------------------------------------------------------------------------
// Weight transpose + split into packed frag layout (unchanged).
// ---------------------------------------------------------------------------
__global__ __launch_bounds__(256) void wsplit_k(
    const float* __restrict__ W_in, const float* __restrict__ Wq,
    const float* __restrict__ Wk, const float* __restrict__ Wv,
    const float* __restrict__ Wo, const float* __restrict__ Wf1,
    const float* __restrict__ Wf2, const float* __restrict__ Ws1,
    const float* __restrict__ Wout,
    f16* __restrict__ WinP, f16* __restrict__ WqkvP, f16* __restrict__ WoP,
    f16* __restrict__ Wf1P, f16* __restrict__ Wf2P, f16* __restrict__ Ws1P,
    f16* __restrict__ WoutP)
{
  const int y = blockIdx.y;
  const long idx = (long)blockIdx.x * 256 + threadIdx.x;
  int Npad, Kpad, Ksrc;
  f16* dst;
  switch (y) {
    case 0: Npad = 256; Kpad = 288; Ksrc = 257; dst = WinP;  break;
    case 1: Npad = 768; Kpad = 256; Ksrc = 256; dst = WqkvP; break;
    case 2: Npad = 256; Kpad = 256; Ksrc = 256; dst = WoP;   break;
    case 3: Npad = 512; Kpad = 256; Ksrc = 256; dst = Wf1P;  break;
    case 4: Npad = 256; Kpad = 512; Ksrc = 512; dst = Wf2P;  break;
    case 5: Npad = 128; Kpad = 256; Ksrc = 256; dst = Ws1P;  break;
    default: Npad = 384; Kpad = 256; Ksrc = 256; dst = WoutP; break;
  }
  if (idx >= (long)Npad * Kpad) return;
  const int n = (int)(idx / Kpad), k = (int)(idx % Kpad);
  float v = 0.f;
  if (k < Ksrc) {
    switch (y) {
      case 0: v = W_in[(long)k * 256 + n]; break;
      case 1: { const int sel = n >> 8;
                const float* s = sel == 0 ? Wq : (sel == 1 ? Wk : Wv);
                v = s[(long)k * 256 + (n & 255)]; } break;
      case 2: v = Wo[(long)k * 256 + n]; break;
      case 3: v = Wf1[(long)k * 512 + n]; break;
      case 4: v = Wf2[(long)k * 256 + n]; break;
      case 5: v = Ws1[(long)k * 128 + n]; break;
      default: v = (n < 257) ? Wout[(long)k * 257 + n] : 0.f; break;
    }
  }
  const long base = ((long)(n >> 5) * (Kpad >> 3) + (k >> 3)) * 512 + (n & 31) * 8 + (k & 7);
  const f16 hi = (f16)v;
  dst[base] = hi;
  dst[base + 256] = (f16)(v - (float)hi);
}

// ---------------------------------------------------------------------------
// Per-time-frame attention over channels (unchanged).
// ---------------------------------------------------------------------------
template<int NCc>
__global__ __launch_bounds__(256) void attn_k(
    const float* __restrict__ Q, const float* __restrict__ Ksp,
    const float* __restrict__ Vsp, f16* __restrict__ chi,
    f16* __restrict__ clo, const int* __restrict__ alive)
{
  if (alive && *alive == 0) return;
  const int w = threadIdx.x >> 6;
  const int l = threadIdx.x & 63;
  for (int rr = 0; rr < 4; rr++) {
    const long r = (long)blockIdx.x * 4 + rr;
    const float qv = Q[r * HD + w * DHD + l];
    float sc[NCc];
    #pragma unroll
    for (int c = 0; c < NCc; c++) {
      float p = qv * Ksp[((long)c * RR + r) * HD + w * DHD + l];
      #pragma unroll
      for (int s = 32; s > 0; s >>= 1) p += __shfl_xor(p, s, 64);
      sc[c] = p * 0.125f;
    }
    float m = sc[0];
    #pragma unroll
    for (int c = 1; c < NCc; c++) m = fmaxf(m, sc[c]);
    float a[NCc];
    float den = 0.f;
    #pragma unroll
    for (int c = 0; c < NCc; c++) { a[c] = expf(sc[c] - m); den += a[c]; }
    float cv = 0.f;
    #pragma unroll
    for (int c = 0; c < NCc; c++)
      cv = fmaf(a[c] / den, Vsp[((long)c * RR + r) * HD + w * DHD + l], cv);
    const f16 hi = (f16)cv;
    chi[r * HD + w * DHD + l] = hi;
    clo[r * HD + w * DHD + l] = (f16)(cv - (float)hi);
  }
}

__global__ void init_k(int* flags) {
  if (threadIdx.x < 8) flags[threadIdx.x] = 0;
}

// ---------------------------------------------------------------------------
extern "C" void kernel_launch(void* const* d_in, const int* in_sizes, int n_in,
                              void* d_out, int out_size, void* d_ws, size_t ws_size,
                              hipStream_t stream) {
  const float* x    = (const float*)d_in[0];
  const float* W_in = (const float*)d_in[1];
  const float* b_in = (const float*)d_in[2];
  const float* W_out= (const float*)d_in[3];
  const float* b_out= (const float*)d_in[4];
  const float* Wq   = (const float*)d_in[5];
  const float* bq   = (const float*)d_in[6];
  const float* Wk   = (const float*)d_in[7];
  const float* bk   = (const float*)d_in[8];
  const float* Wv   = (const float*)d_in[9];
  const float* bv   = (const float*)d_in[10];
  const float* Wo   = (const float*)d_in[11];
  const float* bo   = (const float*)d_in[12];
  const float* ln1g = (const float*)d_in[13];
  const float* ln1b = (const float*)d_in[14];
  const float* Wf1  = (const float*)d_in[15];
  const float* bf1  = (const float*)d_in[16];
  const float* Wf2  = (const float*)d_in[17];
  const float* bf2  = (const float*)d_in[18];
  const float* ln2g = (const float*)d_in[19];
  const float* ln2b = (const float*)d_in[20];
  const float* Ws1  = (const float*)d_in[21];
  const float* bs1  = (const float*)d_in[22];
  const float* Ws2  = (const float*)d_in[23];
  const float* bs2  = (const float*)d_in[24];
  const float* psa  = (const float*)d_in[25];
  const float* psb  = (const float*)d_in[26];

  float* ws = (float*)d_ws;
  long off = 0;
  auto alloc = [&](long n) { float* p = ws + off; off += n; return p; };
  float* Ks   = alloc((long)CH * RR * HD);
  float* Vs   = alloc((long)CH * RR * HD);
  float* Qb   = alloc((long)RR * HD);
  f16* lin1hi = (f16*)alloc((long)RR * HD / 2);
  f16* lin1lo = (f16*)alloc((long)RR * HD / 2);
  f16* ctxhi  = (f16*)alloc((long)RR * HD / 2);
  f16* ctxlo  = (f16*)alloc((long)RR * HD / 2);
  f16* h1hi   = (f16*)alloc((long)RR * HD / 2);
  f16* h1lo   = (f16*)alloc((long)RR * HD / 2);
  f16* hhhi   = (f16*)alloc((long)RR * HD / 2);
  f16* hhlo   = (f16*)alloc((long)RR * HD / 2);
  f16* outhi  = (f16*)alloc((long)RR * HD / 2);
  f16* outlo  = (f16*)alloc((long)RR * HD / 2);
  f16* WinP   = (f16*)alloc(2 * 256 * 288 / 2);
  f16* WqkvP  = (f16*)alloc(2 * 768 * 256 / 2);
  f16* WoP    = (f16*)alloc(2 * 256 * 256 / 2);
  f16* Wf1P   = (f16*)alloc(2 * 512 * 256 / 2);
  f16* Wf2P   = (f16*)alloc(2 * 256 * 512 / 2);
  f16* Ws1P   = (f16*)alloc(2 * 128 * 256 / 2);
  f16* WoutP  = (f16*)alloc(2 * 384 * 256 / 2);
  float* cum  = alloc(RR);
  float* rem  = alloc(RR);
  float* still= alloc(RR);
  float* pc   = alloc(RR);
  int* flags  = (int*)alloc(8);

  init_k<<<1, 256, 0, stream>>>(flags);
  wsplit_k<<<dim3(768, 7), 256, 0, stream>>>(
      W_in, Wq, Wk, Wv, Wo, Wf1, Wf2, Ws1, W_out,
      WinP, WqkvP, WoP, Wf1P, Wf2P, Ws1P, WoutP);

  float* pcdst = (float*)d_out + (long)RR * FB;

  for (int ci = 0; ci < CH; ci++) {
    const int* al = (ci == 0) ? nullptr : (flags + ci - 1);
    // lin1 + Q/K/V (fused)
    lin1_qkv<<<256, 512, 0, stream>>>(
        x + (long)ci * TT * FB, (long)CH * TT * FB,
        WinP, b_in, WqkvP, bq, bk, bv,
        lin1hi, lin1lo, Qb,
        Ks + (long)ci * RR * HD, Vs + (long)ci * RR * HD, al);
    // attention over channels 0..ci
    switch (ci) {
      case 0: attn_k<1><<<4096, 256, 0, stream>>>(Qb, Ks, Vs, ctxhi, ctxlo, al); break;
      case 1: attn_k<2><<<4096, 256, 0, stream>>>(Qb, Ks, Vs, ctxhi, ctxlo, al); break;
      case 2: attn_k<3><<<4096, 256, 0, stream>>>(Qb, Ks, Vs, ctxhi, ctxlo, al); break;
      case 3: attn_k<4><<<4096, 256, 0, stream>>>(Qb, Ks, Vs, ctxhi, ctxlo, al); break;
      case 4: attn_k<5><<<4096, 256, 0, stream>>>(Qb, Ks, Vs, ctxhi, ctxlo, al); break;
      case 5: attn_k<6><<<4096, 256, 0, stream>>>(Qb, Ks, Vs, ctxhi, ctxlo, al); break;
      case 6: attn_k<7><<<4096, 256, 0, stream>>>(Qb, Ks, Vs, ctxhi, ctxlo, al); break;
      default: attn_k<8><<<4096, 256, 0, stream>>>(Qb, Ks, Vs, ctxhi, ctxlo, al); break;
    }
    // h1 = LN(lin1 + ctx @ Wo + bo)
    gemm_ln<<<256, 512, 0, stream>>>(
        ctxhi, ctxlo, HD, WoP, bo, lin1hi, lin1lo, ln1g, ln1b,
        h1hi, h1lo, al);
    // hh = LN(h1 + relu(h1@Wf1+bf1)@Wf2+bf2)  (fully fused FFN)
    ffn_ln<<<256, 512, 0, stream>>>(
        h1hi, h1lo, Wf1P, bf1, Wf2P, bf2, ln2g, ln2b, hhhi, hhlo, al);
    // ponder head + ACT update
    if (ci == 0)
      s1_act<1><<<256, 256, 0, stream>>>(
          hhhi, hhlo, Ws1P, bs1, Ws2, bs2, psa, psb,
          cum, rem, still, pc, outhi, outlo, pcdst, nullptr, flags + 0);
    else if (ci < CH - 1)
      s1_act<0><<<256, 256, 0, stream>>>(
          hhhi, hhlo, Ws1P, bs1, Ws2, bs2, psa, psb,
          cum, rem, still, pc, outhi, outlo, pcdst, al, flags + ci);
    else
      act_last<<<2048, 256, 0, stream>>>(
          hhhi, hhlo, cum, rem, still, pc, outhi, outlo, pcdst, al);
  }
  // encoder_out = relu(out @ W_out + b_out)
  gemm2<1><<<dim3(128, 6), 256, 0, stream>>>(
      outhi, outlo, HD, WoutP, b_out, (float*)d_out, FB, FB);
}